// Round 1
// baseline (5923.801 us; speedup 1.0000x reference)
//
#include <hip/hip_runtime.h>
#include <math.h>

static constexpr int NN = 50000;   // nodes
static constexpr int NF = 128;     // features
static constexpr int NH = 64;      // hidden
static constexpr int NE = 1600000; // edges

// ---------------- utility kernels ----------------

__global__ void fill1_k(float* __restrict__ p, int n) {
  int i = blockIdx.x * 256 + threadIdx.x;
  if (i < n) p[i] = 1.0f;
}

__global__ void zero4_k(float4* __restrict__ p, int n4) {
  int i = blockIdx.x * 256 + threadIdx.x;
  if (i < n4) p[i] = make_float4(0.f, 0.f, 0.f, 0.f);
}

// deg[col[e]] += w[e]   (deg pre-filled with 1.0 for the self-loop)
__global__ void degadd_k(const int* __restrict__ col, const float* __restrict__ w,
                         float* __restrict__ deg, int E) {
  int e = blockIdx.x * 256 + threadIdx.x;
  if (e < E) atomicAdd(&deg[col[e]], w[e]);
}

__global__ void rsqrt_k(float* __restrict__ d, int n) {
  int i = blockIdx.x * 256 + threadIdx.x;
  if (i < n) { float v = d[i]; d[i] = (v > 0.f) ? rsqrtf(v) : 0.f; }
}

// nrm[e] = dinv[row[e]] * w[e] * dinv[col[e]]
__global__ void norm_k(const int* __restrict__ row, const int* __restrict__ col,
                       const float* __restrict__ w, const float* __restrict__ dinv,
                       float* __restrict__ nrm, int E) {
  int e = blockIdx.x * 256 + threadIdx.x;
  if (e < E) nrm[e] = dinv[row[e]] * w[e] * dinv[col[e]];
}

// ---------------- small f32 GEMM: Y[N,M] = (X + Xadd?) [N,K] @ W[K,M] ----------------
// 16 rows per block, W staged in LDS. N must be a multiple of 16 (50000 = 3125*16).
template<int K, int M>
__global__ __launch_bounds__(256) void gemm_k(const float* __restrict__ X,
                                              const float* __restrict__ Xadd,
                                              const float* __restrict__ W,
                                              float* __restrict__ Y) {
  __shared__ float Ws[K * M];
  __shared__ float Xs[16][K];
  for (int i = threadIdx.x; i < K * M; i += 256) Ws[i] = W[i];
  int r0 = blockIdx.x * 16;
  for (int i = threadIdx.x; i < 16 * K; i += 256) {
    int r = i / K, k = i % K;
    float v = X[(size_t)(r0 + r) * K + k];
    if (Xadd) v += Xadd[(size_t)(r0 + r) * K + k];
    Xs[r][k] = v;
  }
  __syncthreads();
  constexpr int RPT = 16 * M / 256;  // rows per thread
  constexpr int RS = 256 / M;        // row stride
  int colc = threadIdx.x % M;
  int rb = threadIdx.x / M;
  float acc[RPT];
#pragma unroll
  for (int i = 0; i < RPT; i++) acc[i] = 0.f;
  for (int k = 0; k < K; k++) {
    float wv = Ws[k * M + colc];   // 64 consecutive lanes -> conflict-free
#pragma unroll
    for (int i = 0; i < RPT; i++) acc[i] += Xs[rb + i * RS][k] * wv;  // broadcast
  }
#pragma unroll
  for (int i = 0; i < RPT; i++) {
    int r = r0 + rb + i * RS;
    Y[(size_t)r * M + colc] = acc[i];
  }
}

// ---------------- edge scatter: dst[col] += nrm * src[row], F channels ----------------
template<int F>
__global__ void scatter_k(const int* __restrict__ row, const int* __restrict__ col,
                          const float* __restrict__ nrm, const float* __restrict__ src,
                          float* __restrict__ dst, int E) {
  constexpr int CH = F / 4;  // threads per edge
  int idx = blockIdx.x * 256 + threadIdx.x;
  int e = idx / CH;
  if (e >= E) return;
  int c4 = (idx % CH) * 4;
  int r = row[e], c = col[e];
  float nm = nrm[e];
  float4 v = *(const float4*)(src + (size_t)r * F + c4);
  float* d = dst + (size_t)c * F + c4;
  atomicAdd(d + 0, nm * v.x);
  atomicAdd(d + 1, nm * v.y);
  atomicAdd(d + 2, nm * v.z);
  atomicAdd(d + 3, nm * v.w);
}

// ---------------- epilogue: agg = act(agg + dinv^2 * xw + bias), in place ----------------
template<int F, int ACT>  // ACT: 1 relu, 2 sigmoid
__global__ void finish_k(float* __restrict__ agg, const float* __restrict__ xw,
                         const float* __restrict__ dinv, const float* __restrict__ bias) {
  constexpr int CH = F / 4;
  int idx = blockIdx.x * 256 + threadIdx.x;
  if (idx >= NN * CH) return;
  int i = idx / CH;
  int c4 = (idx % CH) * 4;
  float di = dinv[i];
  float sl = di * di;  // self-loop norm: dinv[i] * 1 * dinv[i]
  float4 a = *(const float4*)(agg + (size_t)i * F + c4);
  float4 x = *(const float4*)(xw + (size_t)i * F + c4);
  float4 b = *(const float4*)(bias + c4);
  float o0 = a.x + sl * x.x + b.x;
  float o1 = a.y + sl * x.y + b.y;
  float o2 = a.z + sl * x.z + b.z;
  float o3 = a.w + sl * x.w + b.w;
  if (ACT == 1) {
    o0 = fmaxf(o0, 0.f); o1 = fmaxf(o1, 0.f); o2 = fmaxf(o2, 0.f); o3 = fmaxf(o3, 0.f);
  } else {
    o0 = 1.f / (1.f + expf(-o0)); o1 = 1.f / (1.f + expf(-o1));
    o2 = 1.f / (1.f + expf(-o2)); o3 = 1.f / (1.f + expf(-o3));
  }
  *(float4*)(agg + (size_t)i * F + c4) = make_float4(o0, o1, o2, o3);
}

// ---------------- edge probs: ep[e] = sigmoid(dot(z[row[e]], z[col[e]])) ----------------
// 16 lanes per edge, 8 floats (2x float4) per lane.
__global__ void eprob_k(const int* __restrict__ row, const int* __restrict__ col,
                        const float* __restrict__ z, float* __restrict__ ep, int E) {
  int idx = blockIdx.x * 256 + threadIdx.x;
  int e = idx >> 4;
  if (e >= E) return;
  int l = idx & 15;
  const float4* zr = (const float4*)(z + (size_t)row[e] * NF);
  const float4* zc = (const float4*)(z + (size_t)col[e] * NF);
  float4 a = zr[2 * l], b = zc[2 * l];
  float s = a.x * b.x + a.y * b.y + a.z * b.z + a.w * b.w;
  a = zr[2 * l + 1]; b = zc[2 * l + 1];
  s += a.x * b.x + a.y * b.y + a.z * b.z + a.w * b.w;
  s += __shfl_xor(s, 1);
  s += __shfl_xor(s, 2);
  s += __shfl_xor(s, 4);
  s += __shfl_xor(s, 8);
  if (l == 0) ep[e] = 1.f / (1.f + expf(-s));
}

// ---------------- final: sum over relu(agg + dinv2^2*encW + bd1) * wfc ----------------
__global__ __launch_bounds__(256) void final_k(const float* __restrict__ agg,
                                               const float* __restrict__ encW,
                                               const float* __restrict__ dinv2,
                                               const float* __restrict__ bd1,
                                               const float* __restrict__ wfc,
                                               float* __restrict__ partial) {
  int idx = blockIdx.x * 256 + threadIdx.x;  // one float4 (4 channels) per thread
  float s = 0.f;
  if (idx < NN * (NH / 4)) {
    int i = idx >> 4;
    int c4 = (idx & 15) * 4;
    float di = dinv2[i];
    float sl = di * di;
    float4 a = *(const float4*)(agg + (size_t)i * NH + c4);
    float4 x = *(const float4*)(encW + (size_t)i * NH + c4);
    float4 b = *(const float4*)(bd1 + c4);
    float4 w = *(const float4*)(wfc + (size_t)idx * 4);
    s = fmaxf(a.x + sl * x.x + b.x, 0.f) * w.x +
        fmaxf(a.y + sl * x.y + b.y, 0.f) * w.y +
        fmaxf(a.z + sl * x.z + b.z, 0.f) * w.z +
        fmaxf(a.w + sl * x.w + b.w, 0.f) * w.w;
  }
  // full-wave (64) reduce
  s += __shfl_xor(s, 1);
  s += __shfl_xor(s, 2);
  s += __shfl_xor(s, 4);
  s += __shfl_xor(s, 8);
  s += __shfl_xor(s, 16);
  s += __shfl_xor(s, 32);
  __shared__ float ws[4];
  if ((threadIdx.x & 63) == 0) ws[threadIdx.x >> 6] = s;
  __syncthreads();
  if (threadIdx.x == 0) atomicAdd(partial, ws[0] + ws[1] + ws[2] + ws[3]);
}

__global__ void sigmoid_scalar_k(const float* __restrict__ partial,
                                 const float* __restrict__ bfc,
                                 float* __restrict__ out) {
  if (threadIdx.x == 0) out[0] = 1.f / (1.f + expf(-(partial[0] + bfc[0])));
}

// ---------------- launch ----------------

extern "C" void kernel_launch(void* const* d_in, const int* in_sizes, int n_in,
                              void* d_out, int out_size, void* d_ws, size_t ws_size,
                              hipStream_t stream) {
  const float* features = (const float*)d_in[0];
  const int* edge_index = (const int*)d_in[1];  // [2, E] int32 (JAX x64 disabled)
  const float* edge_attr = (const float*)d_in[2];
  const float* Wg1 = (const float*)d_in[3];
  const float* bg1 = (const float*)d_in[4];
  const float* Wg2 = (const float*)d_in[5];
  const float* bg2 = (const float*)d_in[6];
  const float* Wd1 = (const float*)d_in[7];
  const float* bd1 = (const float*)d_in[8];
  const float* wfc = (const float*)d_in[9];
  const float* bfc = (const float*)d_in[10];
  float* out = (float*)d_out;

  const int* row = edge_index;
  const int* col = edge_index + NE;

  // workspace layout (floats)
  float* ws = (float*)d_ws;
  float* dinv  = ws;                 // 50048
  float* dinv2 = dinv + 50048;       // 50048
  float* nrm   = dinv2 + 50048;      // 1600000 (reused for norm2)
  float* xw64  = nrm + NE;           // 3200000 (xw, later encW)
  float* agg64 = xw64 + NN * NH;     // 3200000 (agg1 -> h in place, later agg3)
  float* hw128 = agg64 + NN * NH;    // 6400000
  float* z128  = hw128 + NN * NF;    // 6400000 (agg2 -> z in place)
  float* ep    = z128 + NN * NF;     // 1600000
  float* partial = ep + NE;          // 16

  const int GN  = (NN + 255) / 256;      // 196
  const int GE  = (NE + 255) / 256;      // 6250
  const int GG  = NN / 16;               // 3125 (gemm blocks)
  const int GS64  = NE * (NH / 4) / 256; // 100000
  const int GS128 = NE * (NF / 4) / 256; // 200000
  const int GF64  = NN * (NH / 4) / 256 + 1;
  const int GF128 = NN * (NF / 4) / 256 + 1;
  const int GEP = NE * 16 / 256;         // 100000

  // --- deg / dinv / norm for generator convs ---
  fill1_k<<<GN, 256, 0, stream>>>(dinv, NN);
  degadd_k<<<GE, 256, 0, stream>>>(col, edge_attr, dinv, NE);
  rsqrt_k<<<GN, 256, 0, stream>>>(dinv, NN);
  norm_k<<<GE, 256, 0, stream>>>(row, col, edge_attr, dinv, nrm, NE);

  // --- conv1: h = relu(prop(features @ Wg1) + bg1) ---
  gemm_k<NF, NH><<<GG, 256, 0, stream>>>(features, nullptr, Wg1, xw64);
  zero4_k<<<NN * NH / 4 / 256, 256, 0, stream>>>((float4*)agg64, NN * NH / 4);
  scatter_k<NH><<<GS64, 256, 0, stream>>>(row, col, nrm, xw64, agg64, NE);
  finish_k<NH, 1><<<GF64, 256, 0, stream>>>(agg64, xw64, dinv, bg1);

  // --- conv2: z = sigmoid(prop(h @ Wg2) + bg2) ---
  gemm_k<NH, NF><<<GG, 256, 0, stream>>>(agg64, nullptr, Wg2, hw128);
  zero4_k<<<NN * NF / 4 / 256, 256, 0, stream>>>((float4*)z128, NN * NF / 4);
  scatter_k<NF><<<GS128, 256, 0, stream>>>(row, col, nrm, hw128, z128, NE);
  finish_k<NF, 2><<<GF128, 256, 0, stream>>>(z128, hw128, dinv, bg2);

  // --- edge probs ---
  eprob_k<<<GEP, 256, 0, stream>>>(row, col, z128, ep, NE);

  // --- discriminator deg / norm (weights = edge probs) ---
  fill1_k<<<GN, 256, 0, stream>>>(dinv2, NN);
  degadd_k<<<GE, 256, 0, stream>>>(col, ep, dinv2, NE);
  rsqrt_k<<<GN, 256, 0, stream>>>(dinv2, NN);
  norm_k<<<GE, 256, 0, stream>>>(row, col, ep, dinv2, nrm, NE);

  // --- disc conv: d = relu(prop((z + features) @ Wd1) + bd1), fused with final dot ---
  gemm_k<NF, NH><<<GG, 256, 0, stream>>>(z128, features, Wd1, xw64);
  zero4_k<<<NN * NH / 4 / 256, 256, 0, stream>>>((float4*)agg64, NN * NH / 4);
  scatter_k<NH><<<GS64, 256, 0, stream>>>(row, col, nrm, xw64, agg64, NE);

  zero4_k<<<1, 256, 0, stream>>>((float4*)partial, 4);
  final_k<<<GF64 - 1 + 1, 256, 0, stream>>>(agg64, xw64, dinv2, bd1, wfc, partial);
  sigmoid_scalar_k<<<1, 64, 0, stream>>>(partial, bfc, out);
}

// Round 2
// 1211.517 us; speedup vs baseline: 4.8896x; 4.8896x over previous
//
#include <hip/hip_runtime.h>
#include <math.h>

static constexpr int NN = 50000;   // nodes
static constexpr int NF = 128;     // features
static constexpr int NH = 64;      // hidden
static constexpr int NE = 1600000; // edges

// ---------------- utility kernels ----------------

__global__ void fill1_k(float* __restrict__ p, int n) {
  int i = blockIdx.x * 256 + threadIdx.x;
  if (i < n) p[i] = 1.0f;
}

__global__ void zeroI_k(int* __restrict__ p, int n) {
  int i = blockIdx.x * 256 + threadIdx.x;
  if (i < n) p[i] = 0;
}

// deg[col[e]] += w[e]   (deg pre-filled with 1.0 for the self-loop)
__global__ void degadd_k(const int* __restrict__ col, const float* __restrict__ w,
                         float* __restrict__ deg, int E) {
  int e = blockIdx.x * 256 + threadIdx.x;
  if (e < E) atomicAdd(&deg[col[e]], w[e]);
}

__global__ void rsqrt_k(float* __restrict__ d, int n) {
  int i = blockIdx.x * 256 + threadIdx.x;
  if (i < n) { float v = d[i]; d[i] = (v > 0.f) ? rsqrtf(v) : 0.f; }
}

// ---------------- CSR build ----------------

__global__ void histI_k(const int* __restrict__ col, int* __restrict__ counts, int E) {
  int e = blockIdx.x * 256 + threadIdx.x;
  if (e < E) atomicAdd(&counts[col[e]], 1);
}

// single-block exclusive scan over counts[0..NN) -> rowstart[0..NN], copy to cursor
__global__ __launch_bounds__(1024) void scan_k(const int* __restrict__ counts,
                                               int* __restrict__ rowstart,
                                               int* __restrict__ cursor) {
  __shared__ int part[1024];
  constexpr int CH = (NN + 1023) / 1024;  // 49
  int t = threadIdx.x;
  int base = t * CH;
  int local = 0;
  for (int j = 0; j < CH; j++) {
    int idx = base + j;
    local += (idx < NN) ? counts[idx] : 0;
  }
  part[t] = local;
  __syncthreads();
  for (int off = 1; off < 1024; off <<= 1) {
    int v = (t >= off) ? part[t - off] : 0;
    __syncthreads();
    part[t] += v;
    __syncthreads();
  }
  int ex = (t == 0) ? 0 : part[t - 1];
  for (int j = 0; j < CH; j++) {
    int idx = base + j;
    if (idx < NN) {
      rowstart[idx] = ex;
      cursor[idx] = ex;
      ex += counts[idx];
    }
  }
  if (t == 1023) rowstart[NN] = part[1023];
}

// scatter edges into col-sorted order; nrm_s = dinv[row]*w (dinv[col] applied in agg)
__global__ void permute_k(const int* __restrict__ row, const int* __restrict__ col,
                          const float* __restrict__ w, const float* __restrict__ dinv,
                          int* __restrict__ cursor, int* __restrict__ row_s,
                          float* __restrict__ nrm_s, int E) {
  int e = blockIdx.x * 256 + threadIdx.x;
  if (e >= E) return;
  int c = col[e];
  int p = atomicAdd(&cursor[c], 1);
  int r = row[e];
  row_s[p] = r;
  nrm_s[p] = dinv[r] * w[e];
}

// disc norm over sorted edges: nrm_s = dinv2[row_s]*ep_s
__global__ void norm2_k(const int* __restrict__ row_s, const float* __restrict__ ep_s,
                        const float* __restrict__ dinv2, float* __restrict__ nrm_s, int E) {
  int e = blockIdx.x * 256 + threadIdx.x;
  if (e < E) nrm_s[e] = dinv2[row_s[e]] * ep_s[e];
}

// ---------------- small f32 GEMM: Y[N,M] = (X + Xadd?) [N,K] @ W[K,M] ----------------
template<int K, int M>
__global__ __launch_bounds__(256) void gemm_k(const float* __restrict__ X,
                                              const float* __restrict__ Xadd,
                                              const float* __restrict__ W,
                                              float* __restrict__ Y) {
  __shared__ float Ws[K * M];
  __shared__ float Xs[16][K];
  for (int i = threadIdx.x; i < K * M; i += 256) Ws[i] = W[i];
  int r0 = blockIdx.x * 16;
  for (int i = threadIdx.x; i < 16 * K; i += 256) {
    int r = i / K, k = i % K;
    float v = X[(size_t)(r0 + r) * K + k];
    if (Xadd) v += Xadd[(size_t)(r0 + r) * K + k];
    Xs[r][k] = v;
  }
  __syncthreads();
  constexpr int RPT = 16 * M / 256;
  constexpr int RS = 256 / M;
  int colc = threadIdx.x % M;
  int rb = threadIdx.x / M;
  float acc[RPT];
#pragma unroll
  for (int i = 0; i < RPT; i++) acc[i] = 0.f;
  for (int k = 0; k < K; k++) {
    float wv = Ws[k * M + colc];
#pragma unroll
    for (int i = 0; i < RPT; i++) acc[i] += Xs[rb + i * RS][k] * wv;
  }
#pragma unroll
  for (int i = 0; i < RPT; i++) {
    int r = r0 + rb + i * RS;
    Y[(size_t)r * M + colc] = acc[i];
  }
}

// ---------------- CSR gather-aggregate, fused epilogue ----------------
// one wave per node; out[i] = act(dinv_i*(sum_e nrm_s[e]*xw[row_s[e]] + dinv_i*xw[i]) + bias)
template<int F, int ACT>  // ACT: 1 relu, 2 sigmoid
__global__ __launch_bounds__(256) void agg_k(const int* __restrict__ rowstart,
                                             const int* __restrict__ row_s,
                                             const float* __restrict__ nrm_s,
                                             const float* __restrict__ xw,
                                             const float* __restrict__ dinv,
                                             const float* __restrict__ bias,
                                             float* __restrict__ out) {
  int wid = (blockIdx.x * 256 + threadIdx.x) >> 6;
  if (wid >= NN) return;
  int lane = threadIdx.x & 63;
  int e0 = rowstart[wid], e1 = rowstart[wid + 1];
  constexpr int C = F / 64;  // channels per lane (1 or 2)
  float acc[C];
#pragma unroll
  for (int c = 0; c < C; c++) acc[c] = 0.f;
  for (int e = e0; e < e1; ++e) {
    int r = row_s[e];
    float nm = nrm_s[e];
    const float* src = xw + (size_t)r * F + lane * C;
    if (C == 1) {
      acc[0] = fmaf(nm, src[0], acc[0]);
    } else {
      float2 v = *(const float2*)src;
      acc[0] = fmaf(nm, v.x, acc[0]);
      acc[1] = fmaf(nm, v.y, acc[1]);
    }
  }
  float di = dinv[wid];
  const float* xwi = xw + (size_t)wid * F + lane * C;
  const float* bi = bias + lane * C;
  float o[C];
#pragma unroll
  for (int c = 0; c < C; c++) {
    o[c] = di * (acc[c] + di * xwi[c]) + bi[c];
    if (ACT == 1) o[c] = fmaxf(o[c], 0.f);
    else o[c] = 1.f / (1.f + expf(-o[c]));
  }
  float* op = out + (size_t)wid * F + lane * C;
  if (C == 1) op[0] = o[0];
  else *(float2*)op = make_float2(o[0], o[1]);
}

// ---------------- edge probs per segment + disc degree, fused ----------------
// one wave per node i: for e in segment, ep_s[e] = sigmoid(dot(z[row_s[e]], z[i]));
// dinv2[i] = rsqrt(1 + sum ep_s)
__global__ __launch_bounds__(256) void eprob_seg_k(const int* __restrict__ rowstart,
                                                   const int* __restrict__ row_s,
                                                   const float* __restrict__ z,
                                                   float* __restrict__ ep_s,
                                                   float* __restrict__ dinv2) {
  int wid = (blockIdx.x * 256 + threadIdx.x) >> 6;
  if (wid >= NN) return;
  int lane = threadIdx.x & 63;
  float2 zi = *(const float2*)(z + (size_t)wid * NF + lane * 2);
  int e0 = rowstart[wid], e1 = rowstart[wid + 1];
  float sum = 0.f;
  for (int e = e0; e < e1; ++e) {
    int r = row_s[e];
    float2 zr = *(const float2*)(z + (size_t)r * NF + lane * 2);
    float d = zi.x * zr.x + zi.y * zr.y;
    d += __shfl_xor(d, 1);
    d += __shfl_xor(d, 2);
    d += __shfl_xor(d, 4);
    d += __shfl_xor(d, 8);
    d += __shfl_xor(d, 16);
    d += __shfl_xor(d, 32);
    float p = 1.f / (1.f + expf(-d));
    if (lane == 0) ep_s[e] = p;
    sum += p;  // identical on all lanes
  }
  if (lane == 0) dinv2[wid] = rsqrtf(1.f + sum);
}

// ---------------- final dot: sum(d .* wfc) ----------------
__global__ __launch_bounds__(256) void final_dot_k(const float4* __restrict__ d,
                                                   const float4* __restrict__ wfc,
                                                   float* __restrict__ partial, int n4) {
  int i = blockIdx.x * 256 + threadIdx.x;
  float s = 0.f;
  if (i < n4) {
    float4 a = d[i], w = wfc[i];
    s = a.x * w.x + a.y * w.y + a.z * w.z + a.w * w.w;
  }
  s += __shfl_xor(s, 1);
  s += __shfl_xor(s, 2);
  s += __shfl_xor(s, 4);
  s += __shfl_xor(s, 8);
  s += __shfl_xor(s, 16);
  s += __shfl_xor(s, 32);
  __shared__ float ws[4];
  if ((threadIdx.x & 63) == 0) ws[threadIdx.x >> 6] = s;
  __syncthreads();
  if (threadIdx.x == 0) atomicAdd(partial, ws[0] + ws[1] + ws[2] + ws[3]);
}

__global__ void zeroF_k(float* __restrict__ p, int n) {
  int i = blockIdx.x * 256 + threadIdx.x;
  if (i < n) p[i] = 0.f;
}

__global__ void sigmoid_scalar_k(const float* __restrict__ partial,
                                 const float* __restrict__ bfc,
                                 float* __restrict__ out) {
  if (threadIdx.x == 0) out[0] = 1.f / (1.f + expf(-(partial[0] + bfc[0])));
}

// ---------------- launch ----------------

extern "C" void kernel_launch(void* const* d_in, const int* in_sizes, int n_in,
                              void* d_out, int out_size, void* d_ws, size_t ws_size,
                              hipStream_t stream) {
  const float* features = (const float*)d_in[0];
  const int* edge_index = (const int*)d_in[1];  // [2, E] int32
  const float* edge_attr = (const float*)d_in[2];
  const float* Wg1 = (const float*)d_in[3];
  const float* bg1 = (const float*)d_in[4];
  const float* Wg2 = (const float*)d_in[5];
  const float* bg2 = (const float*)d_in[6];
  const float* Wd1 = (const float*)d_in[7];
  const float* bd1 = (const float*)d_in[8];
  const float* wfc = (const float*)d_in[9];
  const float* bfc = (const float*)d_in[10];
  float* out = (float*)d_out;

  const int* row = edge_index;
  const int* col = edge_index + NE;

  // workspace layout (4B elements)
  char* wsb = (char*)d_ws;
  auto carve = [&](size_t elems) { void* p = wsb; wsb += elems * 4; return p; };
  int*   counts   = (int*)carve(50048);
  int*   rowstart = (int*)carve(50064);
  int*   cursor   = (int*)carve(50048);
  float* dinv     = (float*)carve(50048);
  float* dinv2    = (float*)carve(50048);
  int*   row_s    = (int*)carve(NE);
  float* nrm_s    = (float*)carve(NE);
  float* ep_s     = (float*)carve(NE);
  float* xw64     = (float*)carve((size_t)NN * NH);  // conv1 xw, later disc xw
  float* agg64    = (float*)carve((size_t)NN * NH);  // h, later d
  float* hw128    = (float*)carve((size_t)NN * NF);  // conv2 xw
  float* z128     = (float*)carve((size_t)NN * NF);  // z
  float* partial  = (float*)carve(16);

  const int GN = (NN + 255) / 256;
  const int GE = (NE + 255) / 256;
  const int GG = NN / 16;          // 3125
  const int GW = (NN * 64 + 255) / 256;  // one wave per node -> 12500 blocks

  // --- CSR build + generator deg/norm ---
  zeroI_k<<<GN, 256, 0, stream>>>(counts, NN);
  histI_k<<<GE, 256, 0, stream>>>(col, counts, NE);
  scan_k<<<1, 1024, 0, stream>>>(counts, rowstart, cursor);
  fill1_k<<<GN, 256, 0, stream>>>(dinv, NN);
  degadd_k<<<GE, 256, 0, stream>>>(col, edge_attr, dinv, NE);
  rsqrt_k<<<GN, 256, 0, stream>>>(dinv, NN);
  permute_k<<<GE, 256, 0, stream>>>(row, col, edge_attr, dinv, cursor, row_s, nrm_s, NE);

  // --- conv1: h = relu(prop(features @ Wg1) + bg1) ---
  gemm_k<NF, NH><<<GG, 256, 0, stream>>>(features, nullptr, Wg1, xw64);
  agg_k<NH, 1><<<GW, 256, 0, stream>>>(rowstart, row_s, nrm_s, xw64, dinv, bg1, agg64);

  // --- conv2: z = sigmoid(prop(h @ Wg2) + bg2) ---
  gemm_k<NH, NF><<<GG, 256, 0, stream>>>(agg64, nullptr, Wg2, hw128);
  agg_k<NF, 2><<<GW, 256, 0, stream>>>(rowstart, row_s, nrm_s, hw128, dinv, bg2, z128);

  // --- edge probs + disc degree (fused) ---
  eprob_seg_k<<<GW, 256, 0, stream>>>(rowstart, row_s, z128, ep_s, dinv2);

  // --- disc norm over sorted edges ---
  norm2_k<<<GE, 256, 0, stream>>>(row_s, ep_s, dinv2, nrm_s, NE);

  // --- disc conv: d = relu(prop((z + features) @ Wd1) + bd1) ---
  gemm_k<NF, NH><<<GG, 256, 0, stream>>>(z128, features, Wd1, xw64);
  agg_k<NH, 1><<<GW, 256, 0, stream>>>(rowstart, row_s, nrm_s, xw64, dinv2, bd1, agg64);

  // --- final: sigmoid(dot(d, wfc) + bfc) ---
  zeroF_k<<<1, 64, 0, stream>>>(partial, 16);
  final_dot_k<<<(NN * NH / 4 + 255) / 256, 256, 0, stream>>>(
      (const float4*)agg64, (const float4*)wfc, partial, NN * NH / 4);
  sigmoid_scalar_k<<<1, 64, 0, stream>>>(partial, bfc, out);
}

// Round 3
// 818.113 us; speedup vs baseline: 7.2408x; 1.4809x over previous
//
#include <hip/hip_runtime.h>
#include <math.h>

static constexpr int NN = 50000;   // nodes
static constexpr int NF = 128;     // features
static constexpr int NH = 64;      // hidden
static constexpr int NE = 1600000; // edges

// ---------------- helpers ----------------

__device__ __forceinline__ float bf2f(unsigned u) { return __uint_as_float(u << 16); }
__device__ __forceinline__ unsigned short f2bf(float f) {
  unsigned b = __float_as_uint(f);
  b += 0x7fffu + ((b >> 16) & 1u);  // RNE
  return (unsigned short)(b >> 16);
}
__device__ __forceinline__ float sigm(float x) { return 1.f / (1.f + __expf(-x)); }

// ---------------- utility kernels ----------------

__global__ void fill1_k(float* __restrict__ p, int n) {
  int i = blockIdx.x * 256 + threadIdx.x;
  if (i < n) p[i] = 1.0f;
}

__global__ void zeroI_k(int* __restrict__ p, int n) {
  int i = blockIdx.x * 256 + threadIdx.x;
  if (i < n) p[i] = 0;
}

__global__ void degadd_k(const int* __restrict__ col, const float* __restrict__ w,
                         float* __restrict__ deg, int E) {
  int e = blockIdx.x * 256 + threadIdx.x;
  if (e < E) atomicAdd(&deg[col[e]], w[e]);
}

__global__ void rsqrt_k(float* __restrict__ d, int n) {
  int i = blockIdx.x * 256 + threadIdx.x;
  if (i < n) { float v = d[i]; d[i] = (v > 0.f) ? rsqrtf(v) : 0.f; }
}

// ---------------- CSR build ----------------

__global__ void histI_k(const int* __restrict__ col, int* __restrict__ counts, int E) {
  int e = blockIdx.x * 256 + threadIdx.x;
  if (e < E) atomicAdd(&counts[col[e]], 1);
}

__global__ __launch_bounds__(1024) void scan_k(const int* __restrict__ counts,
                                               int* __restrict__ rowstart,
                                               int* __restrict__ cursor) {
  __shared__ int part[1024];
  constexpr int CH = (NN + 1023) / 1024;  // 49
  int t = threadIdx.x;
  int base = t * CH;
  int local = 0;
  for (int j = 0; j < CH; j++) {
    int idx = base + j;
    local += (idx < NN) ? counts[idx] : 0;
  }
  part[t] = local;
  __syncthreads();
  for (int off = 1; off < 1024; off <<= 1) {
    int v = (t >= off) ? part[t - off] : 0;
    __syncthreads();
    part[t] += v;
    __syncthreads();
  }
  int ex = (t == 0) ? 0 : part[t - 1];
  for (int j = 0; j < CH; j++) {
    int idx = base + j;
    if (idx < NN) {
      rowstart[idx] = ex;
      cursor[idx] = ex;
      ex += counts[idx];
    }
  }
  if (t == 1023) rowstart[NN] = part[1023];
}

// scatter edges into col-sorted order; nrm_s = dinv[row]*w (dinv[col] applied in agg)
__global__ void permute_k(const int* __restrict__ row, const int* __restrict__ col,
                          const float* __restrict__ w, const float* __restrict__ dinv,
                          int* __restrict__ cursor, int* __restrict__ row_s,
                          float* __restrict__ nrm_s, int E) {
  int e = blockIdx.x * 256 + threadIdx.x;
  if (e >= E) return;
  int c = col[e];
  int p = atomicAdd(&cursor[c], 1);
  int r = row[e];
  row_s[p] = r;
  nrm_s[p] = dinv[r] * w[e];
}

// disc norm over sorted edges: nrm_s = dinv2[row_s]*ep_s
__global__ void norm2_k(const int* __restrict__ row_s, const float* __restrict__ ep_s,
                        const float* __restrict__ dinv2, float* __restrict__ nrm_s, int E) {
  int e = blockIdx.x * 256 + threadIdx.x;
  if (e < E) nrm_s[e] = dinv2[row_s[e]] * ep_s[e];
}

// ---------------- small f32 GEMM: Y[N,M] = (X + Xadd?) [N,K] @ W[K,M] ----------------
// ACT: 0 none (no bias), 2 bias+sigmoid. OUTF: write f32 Yf. OUTH: write bf16 Yh.
template<int K, int M, int ACT, bool OUTF, bool OUTH>
__global__ __launch_bounds__(256) void gemm_k(const float* __restrict__ X,
                                              const float* __restrict__ Xadd,
                                              const float* __restrict__ W,
                                              const float* __restrict__ bias,
                                              float* __restrict__ Yf,
                                              unsigned short* __restrict__ Yh) {
  __shared__ float Ws[K * M];
  __shared__ float Xs[16][K];
  for (int i = threadIdx.x; i < K * M; i += 256) Ws[i] = W[i];
  int r0 = blockIdx.x * 16;
  for (int i = threadIdx.x; i < 16 * K; i += 256) {
    int r = i / K, k = i % K;
    float v = X[(size_t)(r0 + r) * K + k];
    if (Xadd) v += Xadd[(size_t)(r0 + r) * K + k];
    Xs[r][k] = v;
  }
  __syncthreads();
  constexpr int RPT = 16 * M / 256;
  constexpr int RS = 256 / M;
  int colc = threadIdx.x % M;
  int rb = threadIdx.x / M;
  float acc[RPT];
#pragma unroll
  for (int i = 0; i < RPT; i++) acc[i] = 0.f;
  for (int k = 0; k < K; k++) {
    float wv = Ws[k * M + colc];
#pragma unroll
    for (int i = 0; i < RPT; i++) acc[i] += Xs[rb + i * RS][k] * wv;
  }
#pragma unroll
  for (int i = 0; i < RPT; i++) {
    int r = r0 + rb + i * RS;
    float o = acc[i];
    if (ACT > 0) o += bias[colc];
    if (ACT == 2) o = sigm(o);
    if (OUTF) Yf[(size_t)r * M + colc] = o;
    if (OUTH) Yh[(size_t)r * M + colc] = f2bf(o);
  }
}

// ---------------- 64-ch CSR gather-aggregate over bf16 src, fused epilogues --------
// one wave per node, 2 edges per iteration (32 lanes x ushort2 each).
// core: o[ch] = dinv_i*(sum_e nrm_s[e]*src[row_s[e]][ch] + dinv_i*src[i][ch])
// MODE 0: relu(o+bias) -> bf16 out   (conv1 -> h)
// MODE 1: o            -> f32 out    (conv2 pre-aggregate of h)
// MODE 2: relu(o+bias) dot wfc -> per-block partial (disc conv + final dot)
template<int MODE>
__global__ __launch_bounds__(256) void agg64_k(const int* __restrict__ rowstart,
                                               const int* __restrict__ row_s,
                                               const float* __restrict__ nrm_s,
                                               const unsigned short* __restrict__ src,
                                               const float* __restrict__ dinv,
                                               const float* __restrict__ bias,
                                               unsigned short* __restrict__ outh,
                                               float* __restrict__ outf,
                                               const float* __restrict__ wfc) {
  int wid = (blockIdx.x * 256 + threadIdx.x) >> 6;  // grid sized exactly: wid < NN
  int lane = threadIdx.x & 63;
  int half = lane >> 5;
  int l = lane & 31;  // channels 2l, 2l+1
  int e0 = rowstart[wid], e1 = rowstart[wid + 1];
  float a0 = 0.f, a1 = 0.f;
  for (int e = e0 + half; e < e1; e += 2) {
    int r = row_s[e];
    float nm = nrm_s[e];
    unsigned v = *(const unsigned*)(src + (size_t)r * 64 + l * 2);
    a0 = fmaf(nm, bf2f(v & 0xffffu), a0);
    a1 = fmaf(nm, bf2f(v >> 16), a1);
  }
  a0 += __shfl_xor(a0, 32);
  a1 += __shfl_xor(a1, 32);
  float di = dinv[wid];
  unsigned sv = *(const unsigned*)(src + (size_t)wid * 64 + l * 2);
  float o0 = di * (a0 + di * bf2f(sv & 0xffffu));
  float o1 = di * (a1 + di * bf2f(sv >> 16));
  if (MODE != 1) {
    float2 b = *(const float2*)(bias + l * 2);
    o0 = fmaxf(o0 + b.x, 0.f);
    o1 = fmaxf(o1 + b.y, 0.f);
  }
  if (MODE == 0) {
    if (half == 0) {
      unsigned p = (unsigned)f2bf(o0) | ((unsigned)f2bf(o1) << 16);
      *(unsigned*)(outh + (size_t)wid * 64 + l * 2) = p;
    }
  } else if (MODE == 1) {
    if (half == 0) *(float2*)(outf + (size_t)wid * 64 + l * 2) = make_float2(o0, o1);
  } else {
    float s = 0.f;
    if (half == 0) {
      float2 w = *(const float2*)(wfc + (size_t)wid * 64 + l * 2);
      s = o0 * w.x + o1 * w.y;
    }
    s += __shfl_xor(s, 1);
    s += __shfl_xor(s, 2);
    s += __shfl_xor(s, 4);
    s += __shfl_xor(s, 8);
    s += __shfl_xor(s, 16);
    s += __shfl_xor(s, 32);
    __shared__ float bs[4];
    if (lane == 0) bs[threadIdx.x >> 6] = s;
    __syncthreads();
    if (threadIdx.x == 0) outf[blockIdx.x] = bs[0] + bs[1] + bs[2] + bs[3];
  }
}

// ---------------- edge probs + disc degree: 16 lanes/edge, 4 edges/wave ----------------
__global__ __launch_bounds__(256) void eprob16_k(const int* __restrict__ rowstart,
                                                 const int* __restrict__ row_s,
                                                 const float* __restrict__ z,
                                                 const unsigned short* __restrict__ zh,
                                                 float* __restrict__ ep_s,
                                                 float* __restrict__ dinv2) {
  int wid = (blockIdx.x * 256 + threadIdx.x) >> 6;  // exact grid: wid < NN
  int lane = threadIdx.x & 63;
  int sub = lane >> 4;  // edge slot 0..3
  int l = lane & 15;    // 8 channels at l*8
  const float* zp = z + (size_t)wid * NF + l * 8;
  float4 zi0 = *(const float4*)zp;
  float4 zi1 = *(const float4*)(zp + 4);
  int e0 = rowstart[wid], e1 = rowstart[wid + 1];
  float sum = 0.f;
  for (int eb = e0; eb < e1; eb += 4) {
    int e = eb + sub;
    bool valid = e < e1;
    int r = row_s[valid ? e : eb];
    uint4 v = *(const uint4*)(zh + (size_t)r * NF + l * 8);
    float d;
    d  = bf2f(v.x & 0xffffu) * zi0.x + bf2f(v.x >> 16) * zi0.y;
    d += bf2f(v.y & 0xffffu) * zi0.z + bf2f(v.y >> 16) * zi0.w;
    d += bf2f(v.z & 0xffffu) * zi1.x + bf2f(v.z >> 16) * zi1.y;
    d += bf2f(v.w & 0xffffu) * zi1.z + bf2f(v.w >> 16) * zi1.w;
    d += __shfl_xor(d, 1);
    d += __shfl_xor(d, 2);
    d += __shfl_xor(d, 4);
    d += __shfl_xor(d, 8);
    if (valid) {
      float p = sigm(d);
      if (l == 0) ep_s[e] = p;
      sum += p;
    }
  }
  sum += __shfl_xor(sum, 16);
  sum += __shfl_xor(sum, 32);
  if (lane == 0) dinv2[wid] = rsqrtf(1.f + sum);
}

// ---------------- final reduce: sigmoid(sum(partials) + bfc) ----------------
__global__ __launch_bounds__(256) void reduce_k(const float* __restrict__ partials, int n,
                                                const float* __restrict__ bfc,
                                                float* __restrict__ out) {
  float s = 0.f;
  for (int i = threadIdx.x; i < n; i += 256) s += partials[i];
  s += __shfl_xor(s, 1);
  s += __shfl_xor(s, 2);
  s += __shfl_xor(s, 4);
  s += __shfl_xor(s, 8);
  s += __shfl_xor(s, 16);
  s += __shfl_xor(s, 32);
  __shared__ float ws4[4];
  if ((threadIdx.x & 63) == 0) ws4[threadIdx.x >> 6] = s;
  __syncthreads();
  if (threadIdx.x == 0) out[0] = sigm(ws4[0] + ws4[1] + ws4[2] + ws4[3] + bfc[0]);
}

// ---------------- launch ----------------

extern "C" void kernel_launch(void* const* d_in, const int* in_sizes, int n_in,
                              void* d_out, int out_size, void* d_ws, size_t ws_size,
                              hipStream_t stream) {
  const float* features = (const float*)d_in[0];
  const int* edge_index = (const int*)d_in[1];  // [2, E] int32
  const float* edge_attr = (const float*)d_in[2];
  const float* Wg1 = (const float*)d_in[3];
  const float* bg1 = (const float*)d_in[4];
  const float* Wg2 = (const float*)d_in[5];
  const float* bg2 = (const float*)d_in[6];
  const float* Wd1 = (const float*)d_in[7];
  const float* bd1 = (const float*)d_in[8];
  const float* wfc = (const float*)d_in[9];
  const float* bfc = (const float*)d_in[10];
  float* out = (float*)d_out;

  const int* row = edge_index;
  const int* col = edge_index + NE;

  // workspace carve (byte-based, 256B aligned)
  char* wsb = (char*)d_ws;
  auto carve = [&](size_t bytes) {
    void* p = wsb;
    wsb += (bytes + 255) & ~(size_t)255;
    return p;
  };
  int*   counts   = (int*)carve(NN * 4);
  int*   rowstart = (int*)carve((NN + 1) * 4);
  int*   cursor   = (int*)carve(NN * 4);
  float* dinv     = (float*)carve(NN * 4);
  float* dinv2    = (float*)carve(NN * 4);
  int*   row_s    = (int*)carve((size_t)NE * 4);
  float* nrm_s    = (float*)carve((size_t)NE * 4);
  float* ep_s     = (float*)carve((size_t)NE * 4);
  unsigned short* xwh = (unsigned short*)carve((size_t)NN * NH * 2);  // conv1 xw / disc xw (bf16)
  unsigned short* hh  = (unsigned short*)carve((size_t)NN * NH * 2);  // h (bf16)
  float* ah   = (float*)carve((size_t)NN * NH * 4);   // prop(h) f32
  float* z128 = (float*)carve((size_t)NN * NF * 4);   // z f32
  unsigned short* zh = (unsigned short*)carve((size_t)NN * NF * 2);   // z bf16
  float* partials = (float*)carve(12500 * 4);

  const int GN = (NN + 255) / 256;
  const int GE = (NE + 255) / 256;
  const int GG = NN / 16;                 // 3125
  const int GW = NN * 64 / 256;           // 12500 (exact)

  // --- CSR build + generator deg/norm ---
  zeroI_k<<<GN, 256, 0, stream>>>(counts, NN);
  histI_k<<<GE, 256, 0, stream>>>(col, counts, NE);
  scan_k<<<1, 1024, 0, stream>>>(counts, rowstart, cursor);
  fill1_k<<<GN, 256, 0, stream>>>(dinv, NN);
  degadd_k<<<GE, 256, 0, stream>>>(col, edge_attr, dinv, NE);
  rsqrt_k<<<GN, 256, 0, stream>>>(dinv, NN);
  permute_k<<<GE, 256, 0, stream>>>(row, col, edge_attr, dinv, cursor, row_s, nrm_s, NE);

  // --- conv1: h = relu(prop(features @ Wg1) + bg1), h in bf16 ---
  gemm_k<NF, NH, 0, false, true><<<GG, 256, 0, stream>>>(features, nullptr, Wg1, nullptr,
                                                         nullptr, xwh);
  agg64_k<0><<<GW, 256, 0, stream>>>(rowstart, row_s, nrm_s, xwh, dinv, bg1, hh, nullptr,
                                     nullptr);

  // --- conv2 (commuted): z = sigmoid(prop(h) @ Wg2 + bg2) ---
  agg64_k<1><<<GW, 256, 0, stream>>>(rowstart, row_s, nrm_s, hh, dinv, nullptr, nullptr, ah,
                                     nullptr);
  gemm_k<NH, NF, 2, true, true><<<GG, 256, 0, stream>>>(ah, nullptr, Wg2, bg2, z128, zh);

  // --- edge probs + disc degree (fused) ---
  eprob16_k<<<GW, 256, 0, stream>>>(rowstart, row_s, z128, zh, ep_s, dinv2);

  // --- disc norm over sorted edges ---
  norm2_k<<<GE, 256, 0, stream>>>(row_s, ep_s, dinv2, nrm_s, NE);

  // --- disc conv fused with final dot: partials[b] = sum relu(...)*wfc ---
  gemm_k<NF, NH, 0, false, true><<<GG, 256, 0, stream>>>(z128, features, Wd1, nullptr,
                                                         nullptr, xwh);
  agg64_k<2><<<GW, 256, 0, stream>>>(rowstart, row_s, nrm_s, xwh, dinv2, bd1, nullptr,
                                     partials, wfc);

  // --- final: sigmoid(sum(partials) + bfc) ---
  reduce_k<<<1, 256, 0, stream>>>(partials, GW, bfc, out);
}

// Round 4
// 689.152 us; speedup vs baseline: 8.5958x; 1.1871x over previous
//
#include <hip/hip_runtime.h>
#include <math.h>

static constexpr int NN = 50000;   // nodes
static constexpr int NF = 128;     // features
static constexpr int NH = 64;      // hidden
static constexpr int NE = 1600000; // edges

// ---------------- helpers ----------------

__device__ __forceinline__ float bf2f(unsigned u) { return __uint_as_float(u << 16); }
__device__ __forceinline__ unsigned short f2bf(float f) {
  unsigned b = __float_as_uint(f);
  b += 0x7fffu + ((b >> 16) & 1u);  // RNE
  return (unsigned short)(b >> 16);
}
__device__ __forceinline__ float sigm(float x) { return 1.f / (1.f + __expf(-x)); }

// ---------------- init / degree ----------------

// counts = 0, deg = 1 (self-loop)
__global__ void init_k(int* __restrict__ counts, float* __restrict__ deg, int n) {
  int i = blockIdx.x * 256 + threadIdx.x;
  if (i < n) { counts[i] = 0; deg[i] = 1.0f; }
}

// fused histogram + weighted degree over col
__global__ void hd_k(const int* __restrict__ col, const float* __restrict__ w,
                     int* __restrict__ counts, float* __restrict__ deg, int E) {
  int e = blockIdx.x * 256 + threadIdx.x;
  if (e < E) {
    int c = col[e];
    atomicAdd(&counts[c], 1);
    atomicAdd(&deg[c], w[e]);
  }
}

__global__ void rsqrt_k(float* __restrict__ d, int n) {
  int i = blockIdx.x * 256 + threadIdx.x;
  if (i < n) { float v = d[i]; d[i] = (v > 0.f) ? rsqrtf(v) : 0.f; }
}

// ---------------- hierarchical scan (3 phases) ----------------

// per-block exclusive scan of 256 counts; block total to bsum
__global__ __launch_bounds__(256) void scanA_k(const int* __restrict__ counts,
                                               int* __restrict__ locEx,
                                               int* __restrict__ bsum) {
  __shared__ int sm[256];
  int t = threadIdx.x;
  int idx = blockIdx.x * 256 + t;
  int v = (idx < NN) ? counts[idx] : 0;
  sm[t] = v;
  __syncthreads();
  for (int off = 1; off < 256; off <<= 1) {
    int u = (t >= off) ? sm[t - off] : 0;
    __syncthreads();
    sm[t] += u;
    __syncthreads();
  }
  if (idx < NN) locEx[idx] = sm[t] - v;  // exclusive
  if (t == 255) bsum[blockIdx.x] = sm[255];
}

// single small block: exclusive scan of block sums (nb <= 256)
__global__ __launch_bounds__(256) void scanB_k(int* __restrict__ bsum, int nb) {
  __shared__ int sm[256];
  int t = threadIdx.x;
  int v = (t < nb) ? bsum[t] : 0;
  sm[t] = v;
  __syncthreads();
  for (int off = 1; off < 256; off <<= 1) {
    int u = (t >= off) ? sm[t - off] : 0;
    __syncthreads();
    sm[t] += u;
    __syncthreads();
  }
  if (t < nb) bsum[t] = sm[t] - v;  // exclusive
}

// add block offsets, produce rowstart + cursor; rowstart[NN] = NE (known total)
__global__ __launch_bounds__(256) void scanC_k(int* __restrict__ rowstart,
                                               const int* __restrict__ bsum,
                                               int* __restrict__ cursor) {
  int idx = blockIdx.x * 256 + threadIdx.x;
  if (idx < NN) {
    int v = rowstart[idx] + bsum[blockIdx.x];
    rowstart[idx] = v;
    cursor[idx] = v;
  }
  if (idx == 0) rowstart[NN] = NE;
}

// ---------------- CSR permute ----------------

// scatter edges into col-sorted order; nrm_s = dinv[row]*w (dinv[col] applied in agg)
__global__ void permute_k(const int* __restrict__ row, const int* __restrict__ col,
                          const float* __restrict__ w, const float* __restrict__ dinv,
                          int* __restrict__ cursor, int* __restrict__ row_s,
                          float* __restrict__ nrm_s, int E) {
  int e = blockIdx.x * 256 + threadIdx.x;
  if (e >= E) return;
  int c = col[e];
  int p = atomicAdd(&cursor[c], 1);
  int r = row[e];
  row_s[p] = r;
  nrm_s[p] = dinv[r] * w[e];
}

// disc norm over sorted edges: nrm_s = dinv2[row_s]*ep_s
__global__ void norm2_k(const int* __restrict__ row_s, const float* __restrict__ ep_s,
                        const float* __restrict__ dinv2, float* __restrict__ nrm_s, int E) {
  int e = blockIdx.x * 256 + threadIdx.x;
  if (e < E) nrm_s[e] = dinv2[row_s[e]] * ep_s[e];
}

// ---------------- small f32 GEMM: Y[N,M] = (X + Xadd?) [N,K] @ W[K,M] ----------------
// ACT: 0 none (no bias), 2 bias+sigmoid. OUTF: write f32 Yf. OUTH: write bf16 Yh.
template<int K, int M, int ACT, bool OUTF, bool OUTH>
__global__ __launch_bounds__(256) void gemm_k(const float* __restrict__ X,
                                              const float* __restrict__ Xadd,
                                              const float* __restrict__ W,
                                              const float* __restrict__ bias,
                                              float* __restrict__ Yf,
                                              unsigned short* __restrict__ Yh) {
  __shared__ float Ws[K * M];
  __shared__ float Xs[16][K];
  for (int i = threadIdx.x; i < K * M; i += 256) Ws[i] = W[i];
  int r0 = blockIdx.x * 16;
  for (int i = threadIdx.x; i < 16 * K; i += 256) {
    int r = i / K, k = i % K;
    float v = X[(size_t)(r0 + r) * K + k];
    if (Xadd) v += Xadd[(size_t)(r0 + r) * K + k];
    Xs[r][k] = v;
  }
  __syncthreads();
  constexpr int RPT = 16 * M / 256;
  constexpr int RS = 256 / M;
  int colc = threadIdx.x % M;
  int rb = threadIdx.x / M;
  float acc[RPT];
#pragma unroll
  for (int i = 0; i < RPT; i++) acc[i] = 0.f;
  for (int k = 0; k < K; k++) {
    float wv = Ws[k * M + colc];
#pragma unroll
    for (int i = 0; i < RPT; i++) acc[i] += Xs[rb + i * RS][k] * wv;
  }
#pragma unroll
  for (int i = 0; i < RPT; i++) {
    int r = r0 + rb + i * RS;
    float o = acc[i];
    if (ACT > 0) o += bias[colc];
    if (ACT == 2) o = sigm(o);
    if (OUTF) Yf[(size_t)r * M + colc] = o;
    if (OUTH) Yh[(size_t)r * M + colc] = f2bf(o);
  }
}

// ---------------- 64-ch CSR gather-aggregate over bf16 src, fused epilogues --------
// one wave per node, 2 edges per iteration (32 lanes x ushort2 each).
// core: o[ch] = dinv_i*(sum_e nrm_s[e]*src[row_s[e]][ch] + dinv_i*src[i][ch])
// MODE 0: relu(o+bias) -> bf16 out   (conv1 -> h)
// MODE 1: o            -> f32 out    (conv2 pre-aggregate of h)
// MODE 2: relu(o+bias) dot wfc -> per-block partial (disc conv + final dot)
template<int MODE>
__global__ __launch_bounds__(256) void agg64_k(const int* __restrict__ rowstart,
                                               const int* __restrict__ row_s,
                                               const float* __restrict__ nrm_s,
                                               const unsigned short* __restrict__ src,
                                               const float* __restrict__ dinv,
                                               const float* __restrict__ bias,
                                               unsigned short* __restrict__ outh,
                                               float* __restrict__ outf,
                                               const float* __restrict__ wfc) {
  int wid = (blockIdx.x * 256 + threadIdx.x) >> 6;  // grid sized exactly: wid < NN
  int lane = threadIdx.x & 63;
  int half = lane >> 5;
  int l = lane & 31;  // channels 2l, 2l+1
  int e0 = rowstart[wid], e1 = rowstart[wid + 1];
  float a0 = 0.f, a1 = 0.f;
  for (int e = e0 + half; e < e1; e += 2) {
    int r = row_s[e];
    float nm = nrm_s[e];
    unsigned v = *(const unsigned*)(src + (size_t)r * 64 + l * 2);
    a0 = fmaf(nm, bf2f(v & 0xffffu), a0);
    a1 = fmaf(nm, bf2f(v >> 16), a1);
  }
  a0 += __shfl_xor(a0, 32);
  a1 += __shfl_xor(a1, 32);
  float di = dinv[wid];
  unsigned sv = *(const unsigned*)(src + (size_t)wid * 64 + l * 2);
  float o0 = di * (a0 + di * bf2f(sv & 0xffffu));
  float o1 = di * (a1 + di * bf2f(sv >> 16));
  if (MODE != 1) {
    float2 b = *(const float2*)(bias + l * 2);
    o0 = fmaxf(o0 + b.x, 0.f);
    o1 = fmaxf(o1 + b.y, 0.f);
  }
  if (MODE == 0) {
    if (half == 0) {
      unsigned p = (unsigned)f2bf(o0) | ((unsigned)f2bf(o1) << 16);
      *(unsigned*)(outh + (size_t)wid * 64 + l * 2) = p;
    }
  } else if (MODE == 1) {
    if (half == 0) *(float2*)(outf + (size_t)wid * 64 + l * 2) = make_float2(o0, o1);
  } else {
    float s = 0.f;
    if (half == 0) {
      float2 w = *(const float2*)(wfc + (size_t)wid * 64 + l * 2);
      s = o0 * w.x + o1 * w.y;
    }
    s += __shfl_xor(s, 1);
    s += __shfl_xor(s, 2);
    s += __shfl_xor(s, 4);
    s += __shfl_xor(s, 8);
    s += __shfl_xor(s, 16);
    s += __shfl_xor(s, 32);
    __shared__ float bs[4];
    if (lane == 0) bs[threadIdx.x >> 6] = s;
    __syncthreads();
    if (threadIdx.x == 0) outf[blockIdx.x] = bs[0] + bs[1] + bs[2] + bs[3];
  }
}

// ---------------- edge probs + disc degree: 16 lanes/edge, 4 edges/wave ----------------
__global__ __launch_bounds__(256) void eprob16_k(const int* __restrict__ rowstart,
                                                 const int* __restrict__ row_s,
                                                 const float* __restrict__ z,
                                                 const unsigned short* __restrict__ zh,
                                                 float* __restrict__ ep_s,
                                                 float* __restrict__ dinv2) {
  int wid = (blockIdx.x * 256 + threadIdx.x) >> 6;  // exact grid: wid < NN
  int lane = threadIdx.x & 63;
  int sub = lane >> 4;  // edge slot 0..3
  int l = lane & 15;    // 8 channels at l*8
  const float* zp = z + (size_t)wid * NF + l * 8;
  float4 zi0 = *(const float4*)zp;
  float4 zi1 = *(const float4*)(zp + 4);
  int e0 = rowstart[wid], e1 = rowstart[wid + 1];
  float sum = 0.f;
  for (int eb = e0; eb < e1; eb += 4) {
    int e = eb + sub;
    bool valid = e < e1;
    int r = row_s[valid ? e : eb];
    uint4 v = *(const uint4*)(zh + (size_t)r * NF + l * 8);
    float d;
    d  = bf2f(v.x & 0xffffu) * zi0.x + bf2f(v.x >> 16) * zi0.y;
    d += bf2f(v.y & 0xffffu) * zi0.z + bf2f(v.y >> 16) * zi0.w;
    d += bf2f(v.z & 0xffffu) * zi1.x + bf2f(v.z >> 16) * zi1.y;
    d += bf2f(v.w & 0xffffu) * zi1.z + bf2f(v.w >> 16) * zi1.w;
    d += __shfl_xor(d, 1);
    d += __shfl_xor(d, 2);
    d += __shfl_xor(d, 4);
    d += __shfl_xor(d, 8);
    if (valid) {
      float p = sigm(d);
      if (l == 0) ep_s[e] = p;
      sum += p;
    }
  }
  sum += __shfl_xor(sum, 16);
  sum += __shfl_xor(sum, 32);
  if (lane == 0) dinv2[wid] = rsqrtf(1.f + sum);
}

// ---------------- final reduce: sigmoid(sum(partials) + bfc) ----------------
__global__ __launch_bounds__(256) void reduce_k(const float* __restrict__ partials, int n,
                                                const float* __restrict__ bfc,
                                                float* __restrict__ out) {
  float s = 0.f;
  for (int i = threadIdx.x; i < n; i += 256) s += partials[i];
  s += __shfl_xor(s, 1);
  s += __shfl_xor(s, 2);
  s += __shfl_xor(s, 4);
  s += __shfl_xor(s, 8);
  s += __shfl_xor(s, 16);
  s += __shfl_xor(s, 32);
  __shared__ float ws4[4];
  if ((threadIdx.x & 63) == 0) ws4[threadIdx.x >> 6] = s;
  __syncthreads();
  if (threadIdx.x == 0) out[0] = sigm(ws4[0] + ws4[1] + ws4[2] + ws4[3] + bfc[0]);
}

// ---------------- launch ----------------

extern "C" void kernel_launch(void* const* d_in, const int* in_sizes, int n_in,
                              void* d_out, int out_size, void* d_ws, size_t ws_size,
                              hipStream_t stream) {
  const float* features = (const float*)d_in[0];
  const int* edge_index = (const int*)d_in[1];  // [2, E] int32
  const float* edge_attr = (const float*)d_in[2];
  const float* Wg1 = (const float*)d_in[3];
  const float* bg1 = (const float*)d_in[4];
  const float* Wg2 = (const float*)d_in[5];
  const float* bg2 = (const float*)d_in[6];
  const float* Wd1 = (const float*)d_in[7];
  const float* bd1 = (const float*)d_in[8];
  const float* wfc = (const float*)d_in[9];
  const float* bfc = (const float*)d_in[10];
  float* out = (float*)d_out;

  const int* row = edge_index;
  const int* col = edge_index + NE;

  // workspace carve (byte-based, 256B aligned)
  char* wsb = (char*)d_ws;
  auto carve = [&](size_t bytes) {
    void* p = wsb;
    wsb += (bytes + 255) & ~(size_t)255;
    return p;
  };
  int*   counts   = (int*)carve(NN * 4);
  int*   rowstart = (int*)carve((NN + 1) * 4);
  int*   cursor   = (int*)carve(NN * 4);
  int*   bsum     = (int*)carve(256 * 4);
  float* dinv     = (float*)carve(NN * 4);
  float* dinv2    = (float*)carve(NN * 4);
  int*   row_s    = (int*)carve((size_t)NE * 4);
  float* nrm_s    = (float*)carve((size_t)NE * 4);
  float* ep_s     = (float*)carve((size_t)NE * 4);
  unsigned short* xwh = (unsigned short*)carve((size_t)NN * NH * 2);  // conv1 xw / disc xw (bf16)
  unsigned short* hh  = (unsigned short*)carve((size_t)NN * NH * 2);  // h (bf16)
  float* ah   = (float*)carve((size_t)NN * NH * 4);   // prop(h) f32
  float* z128 = (float*)carve((size_t)NN * NF * 4);   // z f32
  unsigned short* zh = (unsigned short*)carve((size_t)NN * NF * 2);   // z bf16
  float* partials = (float*)carve(12500 * 4);

  const int GN = (NN + 255) / 256;        // 196
  const int GE = (NE + 255) / 256;        // 6250
  const int GG = NN / 16;                 // 3125
  const int GW = NN * 64 / 256;           // 12500 (exact)

  // --- CSR build + generator deg/norm ---
  init_k<<<GN, 256, 0, stream>>>(counts, dinv, NN);  // dinv holds deg for now
  hd_k<<<GE, 256, 0, stream>>>(col, edge_attr, counts, dinv, NE);
  rsqrt_k<<<GN, 256, 0, stream>>>(dinv, NN);
  scanA_k<<<GN, 256, 0, stream>>>(counts, rowstart, bsum);
  scanB_k<<<1, 256, 0, stream>>>(bsum, GN);
  scanC_k<<<GN, 256, 0, stream>>>(rowstart, bsum, cursor);
  permute_k<<<GE, 256, 0, stream>>>(row, col, edge_attr, dinv, cursor, row_s, nrm_s, NE);

  // --- conv1: h = relu(prop(features @ Wg1) + bg1), h in bf16 ---
  gemm_k<NF, NH, 0, false, true><<<GG, 256, 0, stream>>>(features, nullptr, Wg1, nullptr,
                                                         nullptr, xwh);
  agg64_k<0><<<GW, 256, 0, stream>>>(rowstart, row_s, nrm_s, xwh, dinv, bg1, hh, nullptr,
                                     nullptr);

  // --- conv2 (commuted): z = sigmoid(prop(h) @ Wg2 + bg2) ---
  agg64_k<1><<<GW, 256, 0, stream>>>(rowstart, row_s, nrm_s, hh, dinv, nullptr, nullptr, ah,
                                     nullptr);
  gemm_k<NH, NF, 2, true, true><<<GG, 256, 0, stream>>>(ah, nullptr, Wg2, bg2, z128, zh);

  // --- edge probs + disc degree (fused) ---
  eprob16_k<<<GW, 256, 0, stream>>>(rowstart, row_s, z128, zh, ep_s, dinv2);

  // --- disc norm over sorted edges ---
  norm2_k<<<GE, 256, 0, stream>>>(row_s, ep_s, dinv2, nrm_s, NE);

  // --- disc conv fused with final dot: partials[b] = sum relu(...)*wfc ---
  gemm_k<NF, NH, 0, false, true><<<GG, 256, 0, stream>>>(z128, features, Wd1, nullptr,
                                                         nullptr, xwh);
  agg64_k<2><<<GW, 256, 0, stream>>>(rowstart, row_s, nrm_s, xwh, dinv2, bd1, nullptr,
                                     partials, wfc);

  // --- final: sigmoid(sum(partials) + bfc) ---
  reduce_k<<<1, 256, 0, stream>>>(partials, GW, bfc, out);
}

// Round 5
// 508.739 us; speedup vs baseline: 11.6441x; 1.3546x over previous
//
#include <hip/hip_runtime.h>
#include <math.h>

static constexpr int NN = 50000;   // nodes
static constexpr int NF = 128;     // features
static constexpr int NH = 64;      // hidden
static constexpr int NE = 1600000; // edges

typedef unsigned long long u64;

// ---------------- helpers ----------------

__device__ __forceinline__ float bf2f(unsigned u) { return __uint_as_float(u << 16); }
__device__ __forceinline__ unsigned short f2bf(float f) {
  unsigned b = __float_as_uint(f);
  b += 0x7fffu + ((b >> 16) & 1u);  // RNE
  return (unsigned short)(b >> 16);
}
__device__ __forceinline__ float sigm(float x) { return 1.f / (1.f + __expf(-x)); }

static constexpr float FIX = 33554432.f;  // 2^25 fixed-point scale for degree

// ---------------- init / fused count+degree (one u64 atomic per edge) ----------------

// packed[i] = count<<32 | deg_fixed ; init deg=1.0 (self-loop), count=0
__global__ void init_k(u64* __restrict__ packed, int n) {
  int i = blockIdx.x * 256 + threadIdx.x;
  if (i < n) packed[i] = (u64)(1u << 25);
}

__global__ void hd_k(const int* __restrict__ col, const float* __restrict__ w,
                     u64* __restrict__ packed, int E) {
  int e = blockIdx.x * 256 + threadIdx.x;
  if (e < E) {
    u64 add = ((u64)1 << 32) | (unsigned)(w[e] * FIX + 0.5f);
    atomicAdd(&packed[col[e]], add);
  }
}

// ---------------- hierarchical scan (3 phases); scanA also decodes dinv ----------------

__global__ __launch_bounds__(256) void scanA_k(const u64* __restrict__ packed,
                                               int* __restrict__ locEx,
                                               int* __restrict__ bsum,
                                               float* __restrict__ dinv) {
  __shared__ int sm[256];
  int t = threadIdx.x;
  int idx = blockIdx.x * 256 + t;
  u64 p = (idx < NN) ? packed[idx] : 0;
  int v = (int)(p >> 32);
  if (idx < NN) {
    float deg = (float)(unsigned)(p & 0xffffffffu) * (1.0f / FIX);  // >= 1.0 always
    dinv[idx] = rsqrtf(deg);
  }
  sm[t] = v;
  __syncthreads();
  for (int off = 1; off < 256; off <<= 1) {
    int u = (t >= off) ? sm[t - off] : 0;
    __syncthreads();
    sm[t] += u;
    __syncthreads();
  }
  if (idx < NN) locEx[idx] = sm[t] - v;  // exclusive
  if (t == 255) bsum[blockIdx.x] = sm[255];
}

__global__ __launch_bounds__(256) void scanB_k(int* __restrict__ bsum, int nb) {
  __shared__ int sm[256];
  int t = threadIdx.x;
  int v = (t < nb) ? bsum[t] : 0;
  sm[t] = v;
  __syncthreads();
  for (int off = 1; off < 256; off <<= 1) {
    int u = (t >= off) ? sm[t - off] : 0;
    __syncthreads();
    sm[t] += u;
    __syncthreads();
  }
  if (t < nb) bsum[t] = sm[t] - v;  // exclusive
}

__global__ __launch_bounds__(256) void scanC_k(int* __restrict__ rowstart,
                                               const int* __restrict__ bsum,
                                               int* __restrict__ cursor) {
  int idx = blockIdx.x * 256 + threadIdx.x;
  if (idx < NN) {
    int v = rowstart[idx] + bsum[blockIdx.x];
    rowstart[idx] = v;
    cursor[idx] = v;
  }
  if (idx == 0) rowstart[NN] = NE;
}

// ---------------- CSR permute: packed (row, nrm) 8B edge struct ----------------

__global__ void permute_k(const int* __restrict__ row, const int* __restrict__ col,
                          const float* __restrict__ w, const float* __restrict__ dinv,
                          int* __restrict__ cursor, int2* __restrict__ es, int E) {
  int e = blockIdx.x * 256 + threadIdx.x;
  if (e >= E) return;
  int c = col[e];
  int p = atomicAdd(&cursor[c], 1);
  int r = row[e];
  es[p] = make_int2(r, __float_as_int(dinv[r] * w[e]));
}

// disc norm in place: es[e].y = dinv2[row]*ep_s[e]
__global__ void norm2_k(int2* __restrict__ es, const float* __restrict__ ep_s,
                        const float* __restrict__ dinv2, int E) {
  int e = blockIdx.x * 256 + threadIdx.x;
  if (e < E) {
    int2 v = es[e];
    es[e] = make_int2(v.x, __float_as_int(dinv2[v.x] * ep_s[e]));
  }
}

// ---------------- small f32 GEMM: Y[N,M] = (X(+Xadd)) [N,K] @ W[K,M] ----------------
// XH: X is bf16. ACT: 0 none, 2 bias+sigmoid. OUTF / OUTH: f32 / bf16 outputs.
template<int K, int M, int ACT, bool OUTF, bool OUTH, bool XH>
__global__ __launch_bounds__(256) void gemm_k(const float* __restrict__ X,
                                              const unsigned short* __restrict__ Xh,
                                              const float* __restrict__ Xadd,
                                              const float* __restrict__ W,
                                              const float* __restrict__ bias,
                                              float* __restrict__ Yf,
                                              unsigned short* __restrict__ Yh) {
  __shared__ float Ws[K * M];
  __shared__ float Xs[16][K];
  for (int i = threadIdx.x; i < K * M; i += 256) Ws[i] = W[i];
  int r0 = blockIdx.x * 16;
  for (int i = threadIdx.x; i < 16 * K; i += 256) {
    int r = i / K, k = i % K;
    size_t off = (size_t)(r0 + r) * K + k;
    float v = XH ? bf2f(Xh[off]) : X[off];
    if (Xadd) v += Xadd[off];
    Xs[r][k] = v;
  }
  __syncthreads();
  constexpr int RPT = 16 * M / 256;
  constexpr int RS = 256 / M;
  int colc = threadIdx.x % M;
  int rb = threadIdx.x / M;
  float acc[RPT];
#pragma unroll
  for (int i = 0; i < RPT; i++) acc[i] = 0.f;
  for (int k = 0; k < K; k++) {
    float wv = Ws[k * M + colc];
#pragma unroll
    for (int i = 0; i < RPT; i++) acc[i] += Xs[rb + i * RS][k] * wv;
  }
#pragma unroll
  for (int i = 0; i < RPT; i++) {
    int r = r0 + rb + i * RS;
    float o = acc[i];
    if (ACT > 0) o += bias[colc];
    if (ACT == 2) o = sigm(o);
    if (OUTF) Yf[(size_t)r * M + colc] = o;
    if (OUTH) Yh[(size_t)r * M + colc] = f2bf(o);
  }
}

// ---------------- 64-ch CSR gather-aggregate: 4 edges/iter, 16 lanes x 4ch ----------
// core: o[ch] = dinv_i*(sum_e nrm[e]*src[row[e]][ch] + dinv_i*src[i][ch])
// MODE 0: relu(o+bias) -> bf16 out   (conv1 -> h)
// MODE 1: o            -> f32 out    (conv2 pre-aggregate of h)
// MODE 2: relu(o+bias) dot wfc -> per-block partial (disc conv + final dot)
template<int MODE>
__global__ __launch_bounds__(256) void agg64_k(const int* __restrict__ rowstart,
                                               const int2* __restrict__ es,
                                               const unsigned short* __restrict__ src,
                                               const float* __restrict__ dinv,
                                               const float* __restrict__ bias,
                                               unsigned short* __restrict__ outh,
                                               float* __restrict__ outf,
                                               const float* __restrict__ wfc) {
  int wid = (blockIdx.x * 256 + threadIdx.x) >> 6;  // exact grid: wid < NN
  int lane = threadIdx.x & 63;
  int sub = lane >> 4;  // edge slot 0..3
  int l = lane & 15;    // channels 4l..4l+3
  int e0 = rowstart[wid], e1 = rowstart[wid + 1];
  float a0 = 0.f, a1 = 0.f, a2 = 0.f, a3 = 0.f;
  for (int eb = e0; eb < e1; eb += 4) {
    int e = eb + sub;
    bool valid = e < e1;
    int2 er = es[valid ? e : eb];
    float nm = valid ? __int_as_float(er.y) : 0.f;
    ushort4 v = *(const ushort4*)(src + (size_t)er.x * 64 + l * 4);
    a0 = fmaf(nm, bf2f(v.x), a0);
    a1 = fmaf(nm, bf2f(v.y), a1);
    a2 = fmaf(nm, bf2f(v.z), a2);
    a3 = fmaf(nm, bf2f(v.w), a3);
  }
  a0 += __shfl_xor(a0, 16); a0 += __shfl_xor(a0, 32);
  a1 += __shfl_xor(a1, 16); a1 += __shfl_xor(a1, 32);
  a2 += __shfl_xor(a2, 16); a2 += __shfl_xor(a2, 32);
  a3 += __shfl_xor(a3, 16); a3 += __shfl_xor(a3, 32);
  float di = dinv[wid];
  ushort4 sv = *(const ushort4*)(src + (size_t)wid * 64 + l * 4);
  float o0 = di * (a0 + di * bf2f(sv.x));
  float o1 = di * (a1 + di * bf2f(sv.y));
  float o2 = di * (a2 + di * bf2f(sv.z));
  float o3 = di * (a3 + di * bf2f(sv.w));
  if (MODE != 1) {
    float4 b = *(const float4*)(bias + l * 4);
    o0 = fmaxf(o0 + b.x, 0.f);
    o1 = fmaxf(o1 + b.y, 0.f);
    o2 = fmaxf(o2 + b.z, 0.f);
    o3 = fmaxf(o3 + b.w, 0.f);
  }
  if (MODE == 0) {
    if (sub == 0) {
      ushort4 p;
      p.x = f2bf(o0); p.y = f2bf(o1); p.z = f2bf(o2); p.w = f2bf(o3);
      *(ushort4*)(outh + (size_t)wid * 64 + l * 4) = p;
    }
  } else if (MODE == 1) {
    if (sub == 0) *(float4*)(outf + (size_t)wid * 64 + l * 4) = make_float4(o0, o1, o2, o3);
  } else {
    float s = 0.f;
    if (sub == 0) {
      float4 w4 = *(const float4*)(wfc + (size_t)wid * 64 + l * 4);
      s = o0 * w4.x + o1 * w4.y + o2 * w4.z + o3 * w4.w;
    }
    s += __shfl_xor(s, 1);
    s += __shfl_xor(s, 2);
    s += __shfl_xor(s, 4);
    s += __shfl_xor(s, 8);
    __shared__ float bs[4];
    if (lane == 0) bs[threadIdx.x >> 6] = s;
    __syncthreads();
    if (threadIdx.x == 0) outf[blockIdx.x] = bs[0] + bs[1] + bs[2] + bs[3];
  }
}

// ---------------- edge probs + disc degree: 8 lanes/edge, 8 edges/wave ----------------
__global__ __launch_bounds__(256) void eprob8_k(const int* __restrict__ rowstart,
                                                const int2* __restrict__ es,
                                                const unsigned short* __restrict__ zh,
                                                float* __restrict__ ep_s,
                                                float* __restrict__ dinv2) {
  int wid = (blockIdx.x * 256 + threadIdx.x) >> 6;  // exact grid: wid < NN
  int lane = threadIdx.x & 63;
  int sub = lane >> 3;  // edge slot 0..7
  int l = lane & 7;     // 16 channels at l*16
  const unsigned short* zp = zh + (size_t)wid * NF + l * 16;
  uint4 zA = *(const uint4*)zp;
  uint4 zB = *(const uint4*)(zp + 8);
  float z0 = bf2f(zA.x & 0xffffu), z1 = bf2f(zA.x >> 16);
  float z2 = bf2f(zA.y & 0xffffu), z3 = bf2f(zA.y >> 16);
  float z4 = bf2f(zA.z & 0xffffu), z5 = bf2f(zA.z >> 16);
  float z6 = bf2f(zA.w & 0xffffu), z7 = bf2f(zA.w >> 16);
  float z8 = bf2f(zB.x & 0xffffu), z9 = bf2f(zB.x >> 16);
  float za = bf2f(zB.y & 0xffffu), zb = bf2f(zB.y >> 16);
  float zc = bf2f(zB.z & 0xffffu), zd = bf2f(zB.z >> 16);
  float ze = bf2f(zB.w & 0xffffu), zf = bf2f(zB.w >> 16);
  int e0 = rowstart[wid], e1 = rowstart[wid + 1];
  float sum = 0.f;
  for (int eb = e0; eb < e1; eb += 8) {
    int e = eb + sub;
    bool valid = e < e1;
    int r = es[valid ? e : eb].x;
    const unsigned short* rp = zh + (size_t)r * NF + l * 16;
    uint4 a = *(const uint4*)rp;
    uint4 b = *(const uint4*)(rp + 8);
    float d;
    d  = bf2f(a.x & 0xffffu) * z0 + bf2f(a.x >> 16) * z1;
    d += bf2f(a.y & 0xffffu) * z2 + bf2f(a.y >> 16) * z3;
    d += bf2f(a.z & 0xffffu) * z4 + bf2f(a.z >> 16) * z5;
    d += bf2f(a.w & 0xffffu) * z6 + bf2f(a.w >> 16) * z7;
    d += bf2f(b.x & 0xffffu) * z8 + bf2f(b.x >> 16) * z9;
    d += bf2f(b.y & 0xffffu) * za + bf2f(b.y >> 16) * zb;
    d += bf2f(b.z & 0xffffu) * zc + bf2f(b.z >> 16) * zd;
    d += bf2f(b.w & 0xffffu) * ze + bf2f(b.w >> 16) * zf;
    d += __shfl_xor(d, 1);
    d += __shfl_xor(d, 2);
    d += __shfl_xor(d, 4);
    if (valid && l == 0) {
      float p = sigm(d);
      ep_s[e] = p;
      sum += p;
    }
  }
  sum += __shfl_xor(sum, 8);
  sum += __shfl_xor(sum, 16);
  sum += __shfl_xor(sum, 32);
  if (lane == 0) dinv2[wid] = rsqrtf(1.f + sum);
}

// ---------------- final reduce: sigmoid(sum(partials) + bfc) ----------------
__global__ __launch_bounds__(256) void reduce_k(const float* __restrict__ partials, int n,
                                                const float* __restrict__ bfc,
                                                float* __restrict__ out) {
  float s = 0.f;
  for (int i = threadIdx.x; i < n; i += 256) s += partials[i];
  s += __shfl_xor(s, 1);
  s += __shfl_xor(s, 2);
  s += __shfl_xor(s, 4);
  s += __shfl_xor(s, 8);
  s += __shfl_xor(s, 16);
  s += __shfl_xor(s, 32);
  __shared__ float ws4[4];
  if ((threadIdx.x & 63) == 0) ws4[threadIdx.x >> 6] = s;
  __syncthreads();
  if (threadIdx.x == 0) out[0] = sigm(ws4[0] + ws4[1] + ws4[2] + ws4[3] + bfc[0]);
}

// ---------------- launch ----------------

extern "C" void kernel_launch(void* const* d_in, const int* in_sizes, int n_in,
                              void* d_out, int out_size, void* d_ws, size_t ws_size,
                              hipStream_t stream) {
  const float* features = (const float*)d_in[0];
  const int* edge_index = (const int*)d_in[1];  // [2, E] int32
  const float* edge_attr = (const float*)d_in[2];
  const float* Wg1 = (const float*)d_in[3];
  const float* bg1 = (const float*)d_in[4];
  const float* Wg2 = (const float*)d_in[5];
  const float* bg2 = (const float*)d_in[6];
  const float* Wd1 = (const float*)d_in[7];
  const float* bd1 = (const float*)d_in[8];
  const float* wfc = (const float*)d_in[9];
  const float* bfc = (const float*)d_in[10];
  float* out = (float*)d_out;

  const int* row = edge_index;
  const int* col = edge_index + NE;

  // workspace carve (byte-based, 256B aligned)
  char* wsb = (char*)d_ws;
  auto carve = [&](size_t bytes) {
    void* p = wsb;
    wsb += (bytes + 255) & ~(size_t)255;
    return p;
  };
  u64*   packed   = (u64*)carve((size_t)NN * 8);
  int*   rowstart = (int*)carve((NN + 1) * 4);
  int*   cursor   = (int*)carve(NN * 4);
  int*   bsum     = (int*)carve(256 * 4);
  float* dinv     = (float*)carve(NN * 4);
  float* dinv2    = (float*)carve(NN * 4);
  int2*  es       = (int2*)carve((size_t)NE * 8);   // packed (row, nrm)
  float* ep_s     = (float*)carve((size_t)NE * 4);
  unsigned short* xwh = (unsigned short*)carve((size_t)NN * NH * 2);  // conv1/disc xw bf16
  unsigned short* hh  = (unsigned short*)carve((size_t)NN * NH * 2);  // h bf16
  float* ah   = (float*)carve((size_t)NN * NH * 4);                   // prop(h) f32
  unsigned short* zh = (unsigned short*)carve((size_t)NN * NF * 2);   // z bf16
  float* partials = (float*)carve(12500 * 4);

  const int GN = (NN + 255) / 256;        // 196
  const int GE = (NE + 255) / 256;        // 6250
  const int GG = NN / 16;                 // 3125
  const int GW = NN * 64 / 256;           // 12500 (exact)

  // --- CSR build + generator deg/norm (1 u64 atomic per edge) ---
  init_k<<<GN, 256, 0, stream>>>(packed, NN);
  hd_k<<<GE, 256, 0, stream>>>(col, edge_attr, packed, NE);
  scanA_k<<<GN, 256, 0, stream>>>(packed, rowstart, bsum, dinv);
  scanB_k<<<1, 256, 0, stream>>>(bsum, GN);
  scanC_k<<<GN, 256, 0, stream>>>(rowstart, bsum, cursor);
  permute_k<<<GE, 256, 0, stream>>>(row, col, edge_attr, dinv, cursor, es, NE);

  // --- conv1: h = relu(prop(features @ Wg1) + bg1), h in bf16 ---
  gemm_k<NF, NH, 0, false, true, false><<<GG, 256, 0, stream>>>(
      features, nullptr, nullptr, Wg1, nullptr, nullptr, xwh);
  agg64_k<0><<<GW, 256, 0, stream>>>(rowstart, es, xwh, dinv, bg1, hh, nullptr, nullptr);

  // --- conv2 (commuted): z = sigmoid(prop(h) @ Wg2 + bg2), z in bf16 ---
  agg64_k<1><<<GW, 256, 0, stream>>>(rowstart, es, hh, dinv, nullptr, nullptr, ah, nullptr);
  gemm_k<NH, NF, 2, false, true, false><<<GG, 256, 0, stream>>>(
      ah, nullptr, nullptr, Wg2, bg2, nullptr, zh);

  // --- edge probs + disc degree (fused) ---
  eprob8_k<<<GW, 256, 0, stream>>>(rowstart, es, zh, ep_s, dinv2);

  // --- disc norm in place over edge struct ---
  norm2_k<<<GE, 256, 0, stream>>>(es, ep_s, dinv2, NE);

  // --- disc conv fused with final dot: partials[b] = sum relu(...)*wfc ---
  gemm_k<NF, NH, 0, false, true, true><<<GG, 256, 0, stream>>>(
      nullptr, zh, features, Wd1, nullptr, nullptr, xwh);
  agg64_k<2><<<GW, 256, 0, stream>>>(rowstart, es, xwh, dinv2, bd1, nullptr, partials, wfc);

  // --- final: sigmoid(sum(partials) + bfc) ---
  reduce_k<<<1, 256, 0, stream>>>(partials, GW, bfc, out);
}

// Round 6
// 401.023 us; speedup vs baseline: 14.7717x; 1.2686x over previous
//
#include <hip/hip_runtime.h>
#include <math.h>

static constexpr int NN = 50000;   // nodes
static constexpr int NF = 128;     // features
static constexpr int NH = 64;      // hidden
static constexpr int NE = 1600000; // edges
static constexpr int NBUSED = (NN + 255) / 256;  // 196 buckets (col>>8)
static constexpr int NWG = 256;                  // partition workgroups
static constexpr int CHUNK = NE / NWG;           // 6250 edges per wg

typedef unsigned long long u64;

// ---------------- helpers ----------------

__device__ __forceinline__ float bf2f(unsigned u) { return __uint_as_float(u << 16); }
__device__ __forceinline__ unsigned short f2bf(float f) {
  unsigned b = __float_as_uint(f);
  b += 0x7fffu + ((b >> 16) & 1u);  // RNE
  return (unsigned short)(b >> 16);
}
__device__ __forceinline__ float sigm(float x) { return 1.f / (1.f + __expf(-x)); }

// ================= bucket-sort CSR build (no global per-edge atomics) =================

// counts[g*256 + b] = #edges of workgroup-chunk g with col>>8 == b
__global__ __launch_bounds__(256) void bhist_k(const int* __restrict__ col,
                                               int* __restrict__ counts) {
  __shared__ int cnt[256];
  cnt[threadIdx.x] = 0;
  __syncthreads();
  int g = blockIdx.x;
  int e1 = g * CHUNK + CHUNK;
  for (int e = g * CHUNK + threadIdx.x; e < e1; e += 256)
    atomicAdd(&cnt[col[e] >> 8], 1);
  __syncthreads();
  counts[g * 256 + threadIdx.x] = cnt[threadIdx.x];
}

// counts[g][b] -> global write offset for (chunk g, bucket b); counts[0][b] = bucketStart[b]
__global__ __launch_bounds__(256) void bscan_k(int* __restrict__ counts) {
  __shared__ int sm[256];
  int b = threadIdx.x;
  int tot = 0;
  for (int g = 0; g < NWG; g++) tot += counts[g * 256 + b];  // coalesced per iter
  sm[b] = tot;
  __syncthreads();
  int v = tot;
  for (int off = 1; off < 256; off <<= 1) {
    int u = (b >= off) ? sm[b - off] : 0;
    __syncthreads();
    sm[b] += u;
    __syncthreads();
  }
  int run = sm[b] - v;  // bucketStart[b] (exclusive)
  for (int g = 0; g < NWG; g++) {
    int c = counts[g * 256 + b];
    counts[g * 256 + b] = run;
    run += c;
  }
}

// partition edges into bucket-major order; payload u64 = w<<32 | col_low<<16 | row
__global__ __launch_bounds__(256) void bpart_k(const int* __restrict__ row,
                                               const int* __restrict__ col,
                                               const float* __restrict__ w,
                                               const int* __restrict__ counts,
                                               u64* __restrict__ ebuf) {
  __shared__ int cur[256];
  int g = blockIdx.x;
  cur[threadIdx.x] = counts[g * 256 + threadIdx.x];
  __syncthreads();
  int e1 = g * CHUNK + CHUNK;
  for (int e = g * CHUNK + threadIdx.x; e < e1; e += 256) {
    int c = col[e];
    int p = atomicAdd(&cur[c >> 8], 1);
    u64 pk = ((u64)(unsigned)__float_as_int(w[e]) << 32) |
             ((unsigned)(c & 255) << 16) | (unsigned)row[e];
    ebuf[p] = pk;
  }
}

// per-bucket: count per col + weighted degree (LDS), scan -> rowstart, dinv
__global__ __launch_bounds__(256) void bsortA_k(const u64* __restrict__ ebuf,
                                                const int* __restrict__ counts,
                                                int* __restrict__ rowstart,
                                                float* __restrict__ dinv) {
  __shared__ int cnt[256];
  __shared__ float deg[256];
  __shared__ int sm[256];
  int b = blockIdx.x, t = threadIdx.x;
  cnt[t] = 0;
  deg[t] = 1.0f;  // self-loop weight
  __syncthreads();
  int boff = counts[b];                                // counts[g=0][b] = bucketStart[b]
  int bend = (b < NBUSED - 1) ? counts[b + 1] : NE;
  for (int e = boff + t; e < bend; e += 256) {
    u64 pk = ebuf[e];
    unsigned lo = (unsigned)pk;
    int c = (lo >> 16) & 255;
    atomicAdd(&cnt[c], 1);
    atomicAdd(&deg[c], __uint_as_float((unsigned)(pk >> 32)));
  }
  __syncthreads();
  int v = cnt[t];
  sm[t] = v;
  __syncthreads();
  for (int off = 1; off < 256; off <<= 1) {
    int u = (t >= off) ? sm[t - off] : 0;
    __syncthreads();
    sm[t] += u;
    __syncthreads();
  }
  int colg = b * 256 + t;
  if (colg < NN) {
    rowstart[colg] = boff + sm[t] - v;  // exclusive
    dinv[colg] = rsqrtf(deg[t]);        // deg >= 1 always
  }
  if (b == NBUSED - 1 && t == 0) rowstart[NN] = NE;
}

// per-bucket: place edges at LDS cursors -> es = (row, dinv[row]*w)
__global__ __launch_bounds__(256) void bsortB_k(const u64* __restrict__ ebuf,
                                                const int* __restrict__ counts,
                                                const int* __restrict__ rowstart,
                                                const float* __restrict__ dinv,
                                                int2* __restrict__ es) {
  __shared__ int cur[256];
  int b = blockIdx.x, t = threadIdx.x;
  int colg = b * 256 + t;
  cur[t] = (colg < NN) ? rowstart[colg] : NE;
  __syncthreads();
  int boff = counts[b];
  int bend = (b < NBUSED - 1) ? counts[b + 1] : NE;
  for (int e = boff + t; e < bend; e += 256) {
    u64 pk = ebuf[e];
    unsigned lo = (unsigned)pk;
    int r = lo & 0xffff;
    int c = (lo >> 16) & 255;
    float wv = __uint_as_float((unsigned)(pk >> 32));
    int p = atomicAdd(&cur[c], 1);
    es[p] = make_int2(r, __float_as_int(dinv[r] * wv));
  }
}

// disc norm in place: es[e].y = dinv2[row]*ep_s[e]
__global__ void norm2_k(int2* __restrict__ es, const float* __restrict__ ep_s,
                        const float* __restrict__ dinv2, int E) {
  int e = blockIdx.x * 256 + threadIdx.x;
  if (e < E) {
    int2 v = es[e];
    es[e] = make_int2(v.x, __float_as_int(dinv2[v.x] * ep_s[e]));
  }
}

// ---------------- small f32 GEMM: Y[N,M] = (X(+Xadd)) [N,K] @ W[K,M] ----------------
// XH: X is bf16. ACT: 0 none, 2 bias+sigmoid. OUTF / OUTH: f32 / bf16 outputs.
template<int K, int M, int ACT, bool OUTF, bool OUTH, bool XH>
__global__ __launch_bounds__(256) void gemm_k(const float* __restrict__ X,
                                              const unsigned short* __restrict__ Xh,
                                              const float* __restrict__ Xadd,
                                              const float* __restrict__ W,
                                              const float* __restrict__ bias,
                                              float* __restrict__ Yf,
                                              unsigned short* __restrict__ Yh) {
  __shared__ float Ws[K * M];
  __shared__ float Xs[16][K];
  for (int i = threadIdx.x; i < K * M; i += 256) Ws[i] = W[i];
  int r0 = blockIdx.x * 16;
  for (int i = threadIdx.x; i < 16 * K; i += 256) {
    int r = i / K, k = i % K;
    size_t off = (size_t)(r0 + r) * K + k;
    float v = XH ? bf2f(Xh[off]) : X[off];
    if (Xadd) v += Xadd[off];
    Xs[r][k] = v;
  }
  __syncthreads();
  constexpr int RPT = 16 * M / 256;
  constexpr int RS = 256 / M;
  int colc = threadIdx.x % M;
  int rb = threadIdx.x / M;
  float acc[RPT];
#pragma unroll
  for (int i = 0; i < RPT; i++) acc[i] = 0.f;
  for (int k = 0; k < K; k++) {
    float wv = Ws[k * M + colc];
#pragma unroll
    for (int i = 0; i < RPT; i++) acc[i] += Xs[rb + i * RS][k] * wv;
  }
#pragma unroll
  for (int i = 0; i < RPT; i++) {
    int r = r0 + rb + i * RS;
    float o = acc[i];
    if (ACT > 0) o += bias[colc];
    if (ACT == 2) o = sigm(o);
    if (OUTF) Yf[(size_t)r * M + colc] = o;
    if (OUTH) Yh[(size_t)r * M + colc] = f2bf(o);
  }
}

// ---------------- 64-ch CSR gather-aggregate: 4 edges/iter, 16 lanes x 4ch ----------
// core: o[ch] = dinv_i*(sum_e nrm[e]*src[row[e]][ch] + dinv_i*src[i][ch])
// MODE 0: relu(o+bias) -> bf16 out   (conv1 -> h)
// MODE 1: o            -> f32 out    (conv2 pre-aggregate of h)
// MODE 2: relu(o+bias) dot wfc -> per-block partial (disc conv + final dot)
template<int MODE>
__global__ __launch_bounds__(256) void agg64_k(const int* __restrict__ rowstart,
                                               const int2* __restrict__ es,
                                               const unsigned short* __restrict__ src,
                                               const float* __restrict__ dinv,
                                               const float* __restrict__ bias,
                                               unsigned short* __restrict__ outh,
                                               float* __restrict__ outf,
                                               const float* __restrict__ wfc) {
  int wid = (blockIdx.x * 256 + threadIdx.x) >> 6;  // exact grid: wid < NN
  int lane = threadIdx.x & 63;
  int sub = lane >> 4;  // edge slot 0..3
  int l = lane & 15;    // channels 4l..4l+3
  int e0 = rowstart[wid], e1 = rowstart[wid + 1];
  float a0 = 0.f, a1 = 0.f, a2 = 0.f, a3 = 0.f;
  for (int eb = e0; eb < e1; eb += 4) {
    int e = eb + sub;
    bool valid = e < e1;
    int2 er = es[valid ? e : eb];
    float nm = valid ? __int_as_float(er.y) : 0.f;
    ushort4 v = *(const ushort4*)(src + (size_t)er.x * 64 + l * 4);
    a0 = fmaf(nm, bf2f(v.x), a0);
    a1 = fmaf(nm, bf2f(v.y), a1);
    a2 = fmaf(nm, bf2f(v.z), a2);
    a3 = fmaf(nm, bf2f(v.w), a3);
  }
  a0 += __shfl_xor(a0, 16); a0 += __shfl_xor(a0, 32);
  a1 += __shfl_xor(a1, 16); a1 += __shfl_xor(a1, 32);
  a2 += __shfl_xor(a2, 16); a2 += __shfl_xor(a2, 32);
  a3 += __shfl_xor(a3, 16); a3 += __shfl_xor(a3, 32);
  float di = dinv[wid];
  ushort4 sv = *(const ushort4*)(src + (size_t)wid * 64 + l * 4);
  float o0 = di * (a0 + di * bf2f(sv.x));
  float o1 = di * (a1 + di * bf2f(sv.y));
  float o2 = di * (a2 + di * bf2f(sv.z));
  float o3 = di * (a3 + di * bf2f(sv.w));
  if (MODE != 1) {
    float4 b = *(const float4*)(bias + l * 4);
    o0 = fmaxf(o0 + b.x, 0.f);
    o1 = fmaxf(o1 + b.y, 0.f);
    o2 = fmaxf(o2 + b.z, 0.f);
    o3 = fmaxf(o3 + b.w, 0.f);
  }
  if (MODE == 0) {
    if (sub == 0) {
      ushort4 p;
      p.x = f2bf(o0); p.y = f2bf(o1); p.z = f2bf(o2); p.w = f2bf(o3);
      *(ushort4*)(outh + (size_t)wid * 64 + l * 4) = p;
    }
  } else if (MODE == 1) {
    if (sub == 0) *(float4*)(outf + (size_t)wid * 64 + l * 4) = make_float4(o0, o1, o2, o3);
  } else {
    float s = 0.f;
    if (sub == 0) {
      float4 w4 = *(const float4*)(wfc + (size_t)wid * 64 + l * 4);
      s = o0 * w4.x + o1 * w4.y + o2 * w4.z + o3 * w4.w;
    }
    s += __shfl_xor(s, 1);
    s += __shfl_xor(s, 2);
    s += __shfl_xor(s, 4);
    s += __shfl_xor(s, 8);
    __shared__ float bs[4];
    if (lane == 0) bs[threadIdx.x >> 6] = s;
    __syncthreads();
    if (threadIdx.x == 0) outf[blockIdx.x] = bs[0] + bs[1] + bs[2] + bs[3];
  }
}

// ---------------- edge probs + disc degree: 8 lanes/edge, 8 edges/wave ----------------
__global__ __launch_bounds__(256) void eprob8_k(const int* __restrict__ rowstart,
                                                const int2* __restrict__ es,
                                                const unsigned short* __restrict__ zh,
                                                float* __restrict__ ep_s,
                                                float* __restrict__ dinv2) {
  int wid = (blockIdx.x * 256 + threadIdx.x) >> 6;  // exact grid: wid < NN
  int lane = threadIdx.x & 63;
  int sub = lane >> 3;  // edge slot 0..7
  int l = lane & 7;     // 16 channels at l*16
  const unsigned short* zp = zh + (size_t)wid * NF + l * 16;
  uint4 zA = *(const uint4*)zp;
  uint4 zB = *(const uint4*)(zp + 8);
  float z0 = bf2f(zA.x & 0xffffu), z1 = bf2f(zA.x >> 16);
  float z2 = bf2f(zA.y & 0xffffu), z3 = bf2f(zA.y >> 16);
  float z4 = bf2f(zA.z & 0xffffu), z5 = bf2f(zA.z >> 16);
  float z6 = bf2f(zA.w & 0xffffu), z7 = bf2f(zA.w >> 16);
  float z8 = bf2f(zB.x & 0xffffu), z9 = bf2f(zB.x >> 16);
  float za = bf2f(zB.y & 0xffffu), zb = bf2f(zB.y >> 16);
  float zc = bf2f(zB.z & 0xffffu), zd = bf2f(zB.z >> 16);
  float ze = bf2f(zB.w & 0xffffu), zf = bf2f(zB.w >> 16);
  int e0 = rowstart[wid], e1 = rowstart[wid + 1];
  float sum = 0.f;
  for (int eb = e0; eb < e1; eb += 8) {
    int e = eb + sub;
    bool valid = e < e1;
    int r = es[valid ? e : eb].x;
    const unsigned short* rp = zh + (size_t)r * NF + l * 16;
    uint4 a = *(const uint4*)rp;
    uint4 b = *(const uint4*)(rp + 8);
    float d;
    d  = bf2f(a.x & 0xffffu) * z0 + bf2f(a.x >> 16) * z1;
    d += bf2f(a.y & 0xffffu) * z2 + bf2f(a.y >> 16) * z3;
    d += bf2f(a.z & 0xffffu) * z4 + bf2f(a.z >> 16) * z5;
    d += bf2f(a.w & 0xffffu) * z6 + bf2f(a.w >> 16) * z7;
    d += bf2f(b.x & 0xffffu) * z8 + bf2f(b.x >> 16) * z9;
    d += bf2f(b.y & 0xffffu) * za + bf2f(b.y >> 16) * zb;
    d += bf2f(b.z & 0xffffu) * zc + bf2f(b.z >> 16) * zd;
    d += bf2f(b.w & 0xffffu) * ze + bf2f(b.w >> 16) * zf;
    d += __shfl_xor(d, 1);
    d += __shfl_xor(d, 2);
    d += __shfl_xor(d, 4);
    if (valid && l == 0) {
      float p = sigm(d);
      ep_s[e] = p;
      sum += p;
    }
  }
  sum += __shfl_xor(sum, 8);
  sum += __shfl_xor(sum, 16);
  sum += __shfl_xor(sum, 32);
  if (lane == 0) dinv2[wid] = rsqrtf(1.f + sum);
}

// ---------------- final reduce: sigmoid(sum(partials) + bfc) ----------------
__global__ __launch_bounds__(256) void reduce_k(const float* __restrict__ partials, int n,
                                                const float* __restrict__ bfc,
                                                float* __restrict__ out) {
  float s = 0.f;
  for (int i = threadIdx.x; i < n; i += 256) s += partials[i];
  s += __shfl_xor(s, 1);
  s += __shfl_xor(s, 2);
  s += __shfl_xor(s, 4);
  s += __shfl_xor(s, 8);
  s += __shfl_xor(s, 16);
  s += __shfl_xor(s, 32);
  __shared__ float ws4[4];
  if ((threadIdx.x & 63) == 0) ws4[threadIdx.x >> 6] = s;
  __syncthreads();
  if (threadIdx.x == 0) out[0] = sigm(ws4[0] + ws4[1] + ws4[2] + ws4[3] + bfc[0]);
}

// ---------------- launch ----------------

extern "C" void kernel_launch(void* const* d_in, const int* in_sizes, int n_in,
                              void* d_out, int out_size, void* d_ws, size_t ws_size,
                              hipStream_t stream) {
  const float* features = (const float*)d_in[0];
  const int* edge_index = (const int*)d_in[1];  // [2, E] int32
  const float* edge_attr = (const float*)d_in[2];
  const float* Wg1 = (const float*)d_in[3];
  const float* bg1 = (const float*)d_in[4];
  const float* Wg2 = (const float*)d_in[5];
  const float* bg2 = (const float*)d_in[6];
  const float* Wd1 = (const float*)d_in[7];
  const float* bd1 = (const float*)d_in[8];
  const float* wfc = (const float*)d_in[9];
  const float* bfc = (const float*)d_in[10];
  float* out = (float*)d_out;

  const int* row = edge_index;
  const int* col = edge_index + NE;

  // workspace carve (byte-based, 256B aligned)
  char* wsb = (char*)d_ws;
  auto carve = [&](size_t bytes) {
    void* p = wsb;
    wsb += (bytes + 255) & ~(size_t)255;
    return p;
  };
  int*   counts   = (int*)carve((size_t)NWG * 256 * 4);  // [g][b]
  int*   rowstart = (int*)carve((NN + 1) * 4);
  float* dinv     = (float*)carve(NN * 4);
  float* dinv2    = (float*)carve(NN * 4);
  u64*   ebuf     = (u64*)carve((size_t)NE * 8);    // bucket-partitioned packed edges
  int2*  es       = (int2*)carve((size_t)NE * 8);   // (row, nrm), col-sorted
  float* ep_s     = (float*)carve((size_t)NE * 4);
  unsigned short* xwh = (unsigned short*)carve((size_t)NN * NH * 2);  // conv1/disc xw bf16
  unsigned short* hh  = (unsigned short*)carve((size_t)NN * NH * 2);  // h bf16
  float* ah   = (float*)carve((size_t)NN * NH * 4);                   // prop(h) f32
  unsigned short* zh = (unsigned short*)carve((size_t)NN * NF * 2);   // z bf16
  float* partials = (float*)carve(12500 * 4);

  const int GE = (NE + 255) / 256;        // 6250
  const int GG = NN / 16;                 // 3125
  const int GW = NN * 64 / 256;           // 12500 (exact)

  // --- bucket-sort CSR build (replaces init/hd/scan/permute) ---
  bhist_k<<<NWG, 256, 0, stream>>>(col, counts);
  bscan_k<<<1, 256, 0, stream>>>(counts);
  bpart_k<<<NWG, 256, 0, stream>>>(row, col, edge_attr, counts, ebuf);
  bsortA_k<<<NBUSED, 256, 0, stream>>>(ebuf, counts, rowstart, dinv);
  bsortB_k<<<NBUSED, 256, 0, stream>>>(ebuf, counts, rowstart, dinv, es);

  // --- conv1: h = relu(prop(features @ Wg1) + bg1), h in bf16 ---
  gemm_k<NF, NH, 0, false, true, false><<<GG, 256, 0, stream>>>(
      features, nullptr, nullptr, Wg1, nullptr, nullptr, xwh);
  agg64_k<0><<<GW, 256, 0, stream>>>(rowstart, es, xwh, dinv, bg1, hh, nullptr, nullptr);

  // --- conv2 (commuted): z = sigmoid(prop(h) @ Wg2 + bg2), z in bf16 ---
  agg64_k<1><<<GW, 256, 0, stream>>>(rowstart, es, hh, dinv, nullptr, nullptr, ah, nullptr);
  gemm_k<NH, NF, 2, false, true, false><<<GG, 256, 0, stream>>>(
      ah, nullptr, nullptr, Wg2, bg2, nullptr, zh);

  // --- edge probs + disc degree (fused) ---
  eprob8_k<<<GW, 256, 0, stream>>>(rowstart, es, zh, ep_s, dinv2);

  // --- disc norm in place over edge struct ---
  norm2_k<<<GE, 256, 0, stream>>>(es, ep_s, dinv2, NE);

  // --- disc conv fused with final dot: partials[b] = sum relu(...)*wfc ---
  gemm_k<NF, NH, 0, false, true, true><<<GG, 256, 0, stream>>>(
      nullptr, zh, features, Wd1, nullptr, nullptr, xwh);
  agg64_k<2><<<GW, 256, 0, stream>>>(rowstart, es, xwh, dinv2, bd1, nullptr, partials, wfc);

  // --- final: sigmoid(sum(partials) + bfc) ---
  reduce_k<<<1, 256, 0, stream>>>(partials, GW, bfc, out);
}

// Round 7
// 341.185 us; speedup vs baseline: 17.3624x; 1.1754x over previous
//
#include <hip/hip_runtime.h>
#include <math.h>

static constexpr int NN = 50000;   // nodes
static constexpr int NF = 128;     // features
static constexpr int NH = 64;      // hidden
static constexpr int NE = 1600000; // edges
static constexpr int NBUSED = (NN + 255) / 256;  // 196 buckets (col>>8)
static constexpr int NWG = 256;                  // partition workgroups
static constexpr int CHUNK = NE / NWG;           // 6250 edges per wg

typedef unsigned long long u64;
typedef float f32x2 __attribute__((ext_vector_type(2)));

// ---------------- helpers ----------------

__device__ __forceinline__ float bf2f(unsigned u) { return __uint_as_float(u << 16); }
__device__ __forceinline__ unsigned short f2bf(float f) {
  unsigned b = __float_as_uint(f);
  b += 0x7fffu + ((b >> 16) & 1u);  // RNE
  return (unsigned short)(b >> 16);
}
__device__ __forceinline__ float sigm(float x) { return 1.f / (1.f + __expf(-x)); }
__device__ __forceinline__ unsigned char f2fp8(float f) {
  int v = __builtin_amdgcn_cvt_pk_fp8_f32(f, f, 0, false);
  return (unsigned char)(v & 0xff);
}
// decode 16 fp8 (uint4) -> 16 f32
__device__ __forceinline__ void fp8x16_dec(uint4 v, float* o) {
  f32x2 t;
  t = __builtin_amdgcn_cvt_pk_f32_fp8(v.x, false); o[0] = t.x;  o[1] = t.y;
  t = __builtin_amdgcn_cvt_pk_f32_fp8(v.x, true);  o[2] = t.x;  o[3] = t.y;
  t = __builtin_amdgcn_cvt_pk_f32_fp8(v.y, false); o[4] = t.x;  o[5] = t.y;
  t = __builtin_amdgcn_cvt_pk_f32_fp8(v.y, true);  o[6] = t.x;  o[7] = t.y;
  t = __builtin_amdgcn_cvt_pk_f32_fp8(v.z, false); o[8] = t.x;  o[9] = t.y;
  t = __builtin_amdgcn_cvt_pk_f32_fp8(v.z, true);  o[10] = t.x; o[11] = t.y;
  t = __builtin_amdgcn_cvt_pk_f32_fp8(v.w, false); o[12] = t.x; o[13] = t.y;
  t = __builtin_amdgcn_cvt_pk_f32_fp8(v.w, true);  o[14] = t.x; o[15] = t.y;
}

// ================= bucket-sort CSR build (no global per-edge atomics) =================

__global__ __launch_bounds__(256) void bhist_k(const int* __restrict__ col,
                                               int* __restrict__ counts) {
  __shared__ int cnt[256];
  cnt[threadIdx.x] = 0;
  __syncthreads();
  int g = blockIdx.x;
  int e1 = g * CHUNK + CHUNK;
  for (int e = g * CHUNK + threadIdx.x; e < e1; e += 256)
    atomicAdd(&cnt[col[e] >> 8], 1);
  __syncthreads();
  counts[g * 256 + threadIdx.x] = cnt[threadIdx.x];
}

__global__ __launch_bounds__(256) void bscan_k(int* __restrict__ counts) {
  __shared__ int sm[256];
  int b = threadIdx.x;
  int tot = 0;
  for (int g = 0; g < NWG; g++) tot += counts[g * 256 + b];
  sm[b] = tot;
  __syncthreads();
  int v = tot;
  for (int off = 1; off < 256; off <<= 1) {
    int u = (b >= off) ? sm[b - off] : 0;
    __syncthreads();
    sm[b] += u;
    __syncthreads();
  }
  int run = sm[b] - v;  // bucketStart[b]
  for (int g = 0; g < NWG; g++) {
    int c = counts[g * 256 + b];
    counts[g * 256 + b] = run;
    run += c;
  }
}

// partition edges to bucket-major; payload u64 = w<<32 | col_low<<16 | row
__global__ __launch_bounds__(256) void bpart_k(const int* __restrict__ row,
                                               const int* __restrict__ col,
                                               const float* __restrict__ w,
                                               const int* __restrict__ counts,
                                               u64* __restrict__ ebuf) {
  __shared__ int cur[256];
  int g = blockIdx.x;
  cur[threadIdx.x] = counts[g * 256 + threadIdx.x];
  __syncthreads();
  int e1 = g * CHUNK + CHUNK;
  for (int e = g * CHUNK + threadIdx.x; e < e1; e += 256) {
    int c = col[e];
    int p = atomicAdd(&cur[c >> 8], 1);
    u64 pk = ((u64)(unsigned)__float_as_int(w[e]) << 32) |
             ((unsigned)(c & 255) << 16) | (unsigned)row[e];
    ebuf[p] = pk;
  }
}

// per-bucket: per-col count + weighted degree (LDS), scan -> rowstart, dinv
__global__ __launch_bounds__(256) void bsortA_k(const u64* __restrict__ ebuf,
                                                const int* __restrict__ counts,
                                                int* __restrict__ rowstart,
                                                float* __restrict__ dinv) {
  __shared__ int cnt[256];
  __shared__ float deg[256];
  __shared__ int sm[256];
  int b = blockIdx.x, t = threadIdx.x;
  cnt[t] = 0;
  deg[t] = 1.0f;  // self-loop
  __syncthreads();
  int boff = counts[b];
  int bend = (b < NBUSED - 1) ? counts[b + 1] : NE;
  for (int e = boff + t; e < bend; e += 256) {
    u64 pk = ebuf[e];
    unsigned lo = (unsigned)pk;
    int c = (lo >> 16) & 255;
    atomicAdd(&cnt[c], 1);
    atomicAdd(&deg[c], __uint_as_float((unsigned)(pk >> 32)));
  }
  __syncthreads();
  int v = cnt[t];
  sm[t] = v;
  __syncthreads();
  for (int off = 1; off < 256; off <<= 1) {
    int u = (t >= off) ? sm[t - off] : 0;
    __syncthreads();
    sm[t] += u;
    __syncthreads();
  }
  int colg = b * 256 + t;
  if (colg < NN) {
    rowstart[colg] = boff + sm[t] - v;
    dinv[colg] = rsqrtf(deg[t]);
  }
  if (b == NBUSED - 1 && t == 0) rowstart[NN] = NE;
}

// per-bucket: place edges at LDS cursors -> es = (row, dinv[row]*w)
__global__ __launch_bounds__(256) void bsortB_k(const u64* __restrict__ ebuf,
                                                const int* __restrict__ counts,
                                                const int* __restrict__ rowstart,
                                                const float* __restrict__ dinv,
                                                int2* __restrict__ es) {
  __shared__ int cur[256];
  int b = blockIdx.x, t = threadIdx.x;
  int colg = b * 256 + t;
  cur[t] = (colg < NN) ? rowstart[colg] : NE;
  __syncthreads();
  int boff = counts[b];
  int bend = (b < NBUSED - 1) ? counts[b + 1] : NE;
  for (int e = boff + t; e < bend; e += 256) {
    u64 pk = ebuf[e];
    unsigned lo = (unsigned)pk;
    int r = lo & 0xffff;
    int c = (lo >> 16) & 255;
    float wv = __uint_as_float((unsigned)(pk >> 32));
    int p = atomicAdd(&cur[c], 1);
    es[p] = make_int2(r, __float_as_int(dinv[r] * wv));
  }
}

// ---------------- small f32 GEMM: Y[N,M] = (X(+Xadd)) [N,K] @ W[K,M] ----------------
// XH: X is bf16. ACT: 0 none, 2 bias+sigmoid. OUTF/OUTH/OUT8: f32/bf16/fp8 outputs.
template<int K, int M, int ACT, bool OUTF, bool OUTH, bool XH, bool OUT8>
__global__ __launch_bounds__(256) void gemm_k(const float* __restrict__ X,
                                              const unsigned short* __restrict__ Xh,
                                              const float* __restrict__ Xadd,
                                              const float* __restrict__ W,
                                              const float* __restrict__ bias,
                                              float* __restrict__ Yf,
                                              unsigned short* __restrict__ Yh,
                                              unsigned char* __restrict__ Y8) {
  __shared__ float Ws[K * M];
  __shared__ float Xs[16][K];
  for (int i = threadIdx.x; i < K * M; i += 256) Ws[i] = W[i];
  int r0 = blockIdx.x * 16;
  for (int i = threadIdx.x; i < 16 * K; i += 256) {
    int r = i / K, k = i % K;
    size_t off = (size_t)(r0 + r) * K + k;
    float v = XH ? bf2f(Xh[off]) : X[off];
    if (Xadd) v += Xadd[off];
    Xs[r][k] = v;
  }
  __syncthreads();
  constexpr int RPT = 16 * M / 256;
  constexpr int RS = 256 / M;
  int colc = threadIdx.x % M;
  int rb = threadIdx.x / M;
  float acc[RPT];
#pragma unroll
  for (int i = 0; i < RPT; i++) acc[i] = 0.f;
  for (int k = 0; k < K; k++) {
    float wv = Ws[k * M + colc];
#pragma unroll
    for (int i = 0; i < RPT; i++) acc[i] += Xs[rb + i * RS][k] * wv;
  }
#pragma unroll
  for (int i = 0; i < RPT; i++) {
    int r = r0 + rb + i * RS;
    float o = acc[i];
    if (ACT > 0) o += bias[colc];
    if (ACT == 2) o = sigm(o);
    if (OUTF) Yf[(size_t)r * M + colc] = o;
    if (OUTH) Yh[(size_t)r * M + colc] = f2bf(o);
    if (OUT8) Y8[(size_t)r * M + colc] = f2fp8(o);
  }
}

// ---------------- 64-ch CSR gather-aggregate, fused epilogues --------
// core: o[ch] = dinv_i*(sum_e nrm[e]*src[row[e]][ch] + dinv_i*src[i][ch])
// MODE 0: bf16 src, nrm=es.y;        relu(o+bias) -> bf16 out   (conv1 -> h)
// MODE 1: bf16 src, nrm=es.y;        o            -> f32 out    (conv2 pre-agg)
// MODE 2: fp8 src,  nrm=dinv2[r]*es.y(=ep); relu(o+bias) dot wfc -> block partial
template<int MODE>
__global__ __launch_bounds__(256) void agg64_k(const int* __restrict__ rowstart,
                                               const int2* __restrict__ es,
                                               const unsigned short* __restrict__ src,
                                               const unsigned char* __restrict__ src8,
                                               const float* __restrict__ dinv,
                                               const float* __restrict__ bias,
                                               unsigned short* __restrict__ outh,
                                               float* __restrict__ outf,
                                               const float* __restrict__ wfc) {
  int wid = (blockIdx.x * 256 + threadIdx.x) >> 6;  // exact grid: wid < NN
  int lane = threadIdx.x & 63;
  int e0 = rowstart[wid], e1 = rowstart[wid + 1];
  float di = dinv[wid];

  if (MODE != 2) {
    // ---- bf16 path: 8 edges/iter x 8 lanes x 8ch (16B loads) ----
    int sub = lane >> 3;  // edge slot 0..7
    int l = lane & 7;     // channels l*8 .. l*8+7
    float a[8];
#pragma unroll
    for (int c = 0; c < 8; c++) a[c] = 0.f;
    for (int eb = e0; eb < e1; eb += 8) {
      int e = eb + sub;
      bool valid = e < e1;
      int2 er = es[valid ? e : eb];
      float nm = valid ? __int_as_float(er.y) : 0.f;
      uint4 v = *(const uint4*)(src + (size_t)er.x * 64 + l * 8);
      a[0] = fmaf(nm, bf2f(v.x & 0xffffu), a[0]);
      a[1] = fmaf(nm, bf2f(v.x >> 16), a[1]);
      a[2] = fmaf(nm, bf2f(v.y & 0xffffu), a[2]);
      a[3] = fmaf(nm, bf2f(v.y >> 16), a[3]);
      a[4] = fmaf(nm, bf2f(v.z & 0xffffu), a[4]);
      a[5] = fmaf(nm, bf2f(v.z >> 16), a[5]);
      a[6] = fmaf(nm, bf2f(v.w & 0xffffu), a[6]);
      a[7] = fmaf(nm, bf2f(v.w >> 16), a[7]);
    }
#pragma unroll
    for (int c = 0; c < 8; c++) {
      a[c] += __shfl_xor(a[c], 8);
      a[c] += __shfl_xor(a[c], 16);
      a[c] += __shfl_xor(a[c], 32);
    }
    uint4 sv = *(const uint4*)(src + (size_t)wid * 64 + l * 8);
    float sf[8] = {bf2f(sv.x & 0xffffu), bf2f(sv.x >> 16), bf2f(sv.y & 0xffffu),
                   bf2f(sv.y >> 16),     bf2f(sv.z & 0xffffu), bf2f(sv.z >> 16),
                   bf2f(sv.w & 0xffffu), bf2f(sv.w >> 16)};
    float o[8];
#pragma unroll
    for (int c = 0; c < 8; c++) o[c] = di * (a[c] + di * sf[c]);
    if (MODE == 0) {
      float4 b0 = *(const float4*)(bias + l * 8);
      float4 b1 = *(const float4*)(bias + l * 8 + 4);
      o[0] = fmaxf(o[0] + b0.x, 0.f); o[1] = fmaxf(o[1] + b0.y, 0.f);
      o[2] = fmaxf(o[2] + b0.z, 0.f); o[3] = fmaxf(o[3] + b0.w, 0.f);
      o[4] = fmaxf(o[4] + b1.x, 0.f); o[5] = fmaxf(o[5] + b1.y, 0.f);
      o[6] = fmaxf(o[6] + b1.z, 0.f); o[7] = fmaxf(o[7] + b1.w, 0.f);
      if (sub == 0) {
        uint4 p;
        p.x = (unsigned)f2bf(o[0]) | ((unsigned)f2bf(o[1]) << 16);
        p.y = (unsigned)f2bf(o[2]) | ((unsigned)f2bf(o[3]) << 16);
        p.z = (unsigned)f2bf(o[4]) | ((unsigned)f2bf(o[5]) << 16);
        p.w = (unsigned)f2bf(o[6]) | ((unsigned)f2bf(o[7]) << 16);
        *(uint4*)(outh + (size_t)wid * 64 + l * 8) = p;
      }
    } else {
      if (sub == 0) {
        *(float4*)(outf + (size_t)wid * 64 + l * 8) = make_float4(o[0], o[1], o[2], o[3]);
        *(float4*)(outf + (size_t)wid * 64 + l * 8 + 4) = make_float4(o[4], o[5], o[6], o[7]);
      }
    }
  } else {
    // ---- fp8 path: 16 edges/iter x 4 lanes x 16ch (16B loads) ----
    int sub = lane >> 2;  // edge slot 0..15
    int l = lane & 3;     // channels l*16 .. l*16+15
    float a[16];
#pragma unroll
    for (int c = 0; c < 16; c++) a[c] = 0.f;
    for (int eb = e0; eb < e1; eb += 16) {
      int e = eb + sub;
      bool valid = e < e1;
      int2 er = es[valid ? e : eb];
      float nm = valid ? dinv[er.x] * __int_as_float(er.y) : 0.f;  // dinv2[r]*ep
      uint4 v = *(const uint4*)(src8 + (size_t)er.x * 64 + l * 16);
      float t[16];
      fp8x16_dec(v, t);
#pragma unroll
      for (int c = 0; c < 16; c++) a[c] = fmaf(nm, t[c], a[c]);
    }
#pragma unroll
    for (int c = 0; c < 16; c++) {
      a[c] += __shfl_xor(a[c], 4);
      a[c] += __shfl_xor(a[c], 8);
      a[c] += __shfl_xor(a[c], 16);
      a[c] += __shfl_xor(a[c], 32);
    }
    uint4 sv = *(const uint4*)(src8 + (size_t)wid * 64 + l * 16);
    float sf[16];
    fp8x16_dec(sv, sf);
    float s = 0.f;
    if (sub == 0) {
#pragma unroll
      for (int c = 0; c < 4; c++) {
        float4 b4 = *(const float4*)(bias + l * 16 + c * 4);
        float4 w4 = *(const float4*)(wfc + (size_t)wid * 64 + l * 16 + c * 4);
        float o0 = fmaxf(di * (a[c * 4 + 0] + di * sf[c * 4 + 0]) + b4.x, 0.f);
        float o1 = fmaxf(di * (a[c * 4 + 1] + di * sf[c * 4 + 1]) + b4.y, 0.f);
        float o2 = fmaxf(di * (a[c * 4 + 2] + di * sf[c * 4 + 2]) + b4.z, 0.f);
        float o3 = fmaxf(di * (a[c * 4 + 3] + di * sf[c * 4 + 3]) + b4.w, 0.f);
        s += o0 * w4.x + o1 * w4.y + o2 * w4.z + o3 * w4.w;
      }
    }
    s += __shfl_xor(s, 1);
    s += __shfl_xor(s, 2);
    __shared__ float bs[4];
    if (lane == 0) bs[threadIdx.x >> 6] = s;
    __syncthreads();
    if (threadIdx.x == 0) outf[blockIdx.x] = bs[0] + bs[1] + bs[2] + bs[3];
  }
}

// ------- edge probs + disc degree: fp8 z, 8 lanes/edge, 8 edges/wave; ep -> es.y -------
__global__ __launch_bounds__(256) void eprob8_k(const int* __restrict__ rowstart,
                                                int2* __restrict__ es,
                                                const unsigned char* __restrict__ z8,
                                                float* __restrict__ dinv2) {
  int wid = (blockIdx.x * 256 + threadIdx.x) >> 6;  // exact grid: wid < NN
  int lane = threadIdx.x & 63;
  int sub = lane >> 3;  // edge slot 0..7
  int l = lane & 7;     // 16 channels at l*16
  uint4 zv = *(const uint4*)(z8 + (size_t)wid * NF + l * 16);
  float zi[16];
  fp8x16_dec(zv, zi);
  int e0 = rowstart[wid], e1 = rowstart[wid + 1];
  float sum = 0.f;
  for (int eb = e0; eb < e1; eb += 8) {
    int e = eb + sub;
    bool valid = e < e1;
    int r = es[valid ? e : eb].x;
    uint4 v = *(const uint4*)(z8 + (size_t)r * NF + l * 16);
    float zr[16];
    fp8x16_dec(v, zr);
    float d = 0.f;
#pragma unroll
    for (int c = 0; c < 16; c++) d = fmaf(zr[c], zi[c], d);
    d += __shfl_xor(d, 1);
    d += __shfl_xor(d, 2);
    d += __shfl_xor(d, 4);
    if (valid && l == 0) {
      float p = sigm(d);
      es[e].y = __float_as_int(p);
      sum += p;
    }
  }
  sum += __shfl_xor(sum, 8);
  sum += __shfl_xor(sum, 16);
  sum += __shfl_xor(sum, 32);
  if (lane == 0) dinv2[wid] = rsqrtf(1.f + sum);
}

// ---------------- final reduce: sigmoid(sum(partials) + bfc) ----------------
__global__ __launch_bounds__(256) void reduce_k(const float* __restrict__ partials, int n,
                                                const float* __restrict__ bfc,
                                                float* __restrict__ out) {
  float s = 0.f;
  for (int i = threadIdx.x; i < n; i += 256) s += partials[i];
  s += __shfl_xor(s, 1);
  s += __shfl_xor(s, 2);
  s += __shfl_xor(s, 4);
  s += __shfl_xor(s, 8);
  s += __shfl_xor(s, 16);
  s += __shfl_xor(s, 32);
  __shared__ float ws4[4];
  if ((threadIdx.x & 63) == 0) ws4[threadIdx.x >> 6] = s;
  __syncthreads();
  if (threadIdx.x == 0) out[0] = sigm(ws4[0] + ws4[1] + ws4[2] + ws4[3] + bfc[0]);
}

// ---------------- launch ----------------

extern "C" void kernel_launch(void* const* d_in, const int* in_sizes, int n_in,
                              void* d_out, int out_size, void* d_ws, size_t ws_size,
                              hipStream_t stream) {
  const float* features = (const float*)d_in[0];
  const int* edge_index = (const int*)d_in[1];  // [2, E] int32
  const float* edge_attr = (const float*)d_in[2];
  const float* Wg1 = (const float*)d_in[3];
  const float* bg1 = (const float*)d_in[4];
  const float* Wg2 = (const float*)d_in[5];
  const float* bg2 = (const float*)d_in[6];
  const float* Wd1 = (const float*)d_in[7];
  const float* bd1 = (const float*)d_in[8];
  const float* wfc = (const float*)d_in[9];
  const float* bfc = (const float*)d_in[10];
  float* out = (float*)d_out;

  const int* row = edge_index;
  const int* col = edge_index + NE;

  // workspace carve (byte-based, 256B aligned)
  char* wsb = (char*)d_ws;
  auto carve = [&](size_t bytes) {
    void* p = wsb;
    wsb += (bytes + 255) & ~(size_t)255;
    return p;
  };
  int*   counts   = (int*)carve((size_t)NWG * 256 * 4);  // [g][b]
  int*   rowstart = (int*)carve((NN + 1) * 4);
  float* dinv     = (float*)carve(NN * 4);
  float* dinv2    = (float*)carve(NN * 4);
  u64*   ebuf     = (u64*)carve((size_t)NE * 8);    // bucket-partitioned packed edges
  int2*  es       = (int2*)carve((size_t)NE * 8);   // (row, nrm/ep), col-sorted
  unsigned short* xwh = (unsigned short*)carve((size_t)NN * NH * 2);  // conv1 xw bf16
  unsigned short* hh  = (unsigned short*)carve((size_t)NN * NH * 2);  // h bf16
  float* ah   = (float*)carve((size_t)NN * NH * 4);                   // prop(h) f32
  unsigned short* zh = (unsigned short*)carve((size_t)NN * NF * 2);   // z bf16 (gemm3 in)
  unsigned char* z8  = (unsigned char*)carve((size_t)NN * NF);        // z fp8 (eprob)
  unsigned char* xw8 = (unsigned char*)carve((size_t)NN * NH);        // disc xw fp8
  float* partials = (float*)carve(12500 * 4);

  const int GG = NN / 16;                 // 3125
  const int GW = NN * 64 / 256;           // 12500 (exact)

  // --- bucket-sort CSR build ---
  bhist_k<<<NWG, 256, 0, stream>>>(col, counts);
  bscan_k<<<1, 256, 0, stream>>>(counts);
  bpart_k<<<NWG, 256, 0, stream>>>(row, col, edge_attr, counts, ebuf);
  bsortA_k<<<NBUSED, 256, 0, stream>>>(ebuf, counts, rowstart, dinv);
  bsortB_k<<<NBUSED, 256, 0, stream>>>(ebuf, counts, rowstart, dinv, es);

  // --- conv1: h = relu(prop(features @ Wg1) + bg1), h in bf16 ---
  gemm_k<NF, NH, 0, false, true, false, false><<<GG, 256, 0, stream>>>(
      features, nullptr, nullptr, Wg1, nullptr, nullptr, xwh, nullptr);
  agg64_k<0><<<GW, 256, 0, stream>>>(rowstart, es, xwh, nullptr, dinv, bg1, hh, nullptr,
                                     nullptr);

  // --- conv2 (commuted): z = sigmoid(prop(h) @ Wg2 + bg2), z in bf16 + fp8 ---
  agg64_k<1><<<GW, 256, 0, stream>>>(rowstart, es, hh, nullptr, dinv, nullptr, nullptr, ah,
                                     nullptr);
  gemm_k<NH, NF, 2, false, true, false, true><<<GG, 256, 0, stream>>>(
      ah, nullptr, nullptr, Wg2, bg2, nullptr, zh, z8);

  // --- edge probs + disc degree (fused); ep written into es.y ---
  eprob8_k<<<GW, 256, 0, stream>>>(rowstart, es, z8, dinv2);

  // --- disc conv fused with final dot: partials[b] = sum relu(...)*wfc ---
  gemm_k<NF, NH, 0, false, false, true, true><<<GG, 256, 0, stream>>>(
      nullptr, zh, features, Wd1, nullptr, nullptr, nullptr, xw8);
  agg64_k<2><<<GW, 256, 0, stream>>>(rowstart, es, nullptr, xw8, dinv2, bd1, nullptr,
                                     partials, wfc);

  // --- final: sigmoid(sum(partials) + bfc) ---
  reduce_k<<<1, 256, 0, stream>>>(partials, GW, bfc, out);
}